// Round 1
// baseline (210788.062 us; speedup 1.0000x reference)
//
#include <hip/hip_runtime.h>
#include <math.h>

// ---- model dims ----
#define LAYERS 8
#define WIN    32
#define NH     8
#define DHD    64
#define DM     512
#define DFF    2048
#define NCLS   256
#define MEL    80
#define TT     512

// ---- launch shape: persistent kernel, 64 blocks x 256 threads (1 block/CU) ----
#define GRID   64
#define BLK    256

// wave=64 reductions
__device__ inline float wredsum(float v){
#pragma unroll
  for (int m = 32; m >= 1; m >>= 1) v += __shfl_xor(v, m, 64);
  return v;
}
__device__ inline float wredmax(float v){
#pragma unroll
  for (int m = 32; m >= 1; m >>= 1) v = fmaxf(v, __shfl_xor(v, m, 64));
  return v;
}

// dot(wrow[0:512], vec[0:512]) across one wave; vec typically in LDS
__device__ inline float dot512(const float* __restrict__ wrow, const float* vec, int lane){
  float4 a0 = *(const float4*)(wrow + 4*lane);
  float4 a1 = *(const float4*)(wrow + 256 + 4*lane);
  float4 b0 = *(const float4*)(vec + 4*lane);
  float4 b1 = *(const float4*)(vec + 256 + 4*lane);
  float p = a0.x*b0.x + a0.y*b0.y + a0.z*b0.z + a0.w*b0.w
          + a1.x*b1.x + a1.y*b1.y + a1.z*b1.z + a1.w*b1.w;
  return wredsum(p);
}

__device__ inline float gelu_tanh(float x){
  float x3 = x*x*x;
  return 0.5f*x*(1.0f + tanhf(0.7978845608028654f*(x + 0.044715f*x3)));
}

// global sense-free barrier: monotone generation counter; per-block phase in thread0 reg.
// Arrival RMW (acq_rel, agent) makes each block's prior writes visible to the last
// arriver; its release bump of gen + spinners' acquire load completes the chain.
#define GBAR() do {                                                                   \
    __syncthreads();                                                                  \
    if (threadIdx.x == 0){                                                            \
      bphase++;                                                                       \
      int v_ = __hip_atomic_fetch_add(bar_cnt, 1, __ATOMIC_ACQ_REL,                   \
                                      __HIP_MEMORY_SCOPE_AGENT);                      \
      if (v_ == GRID-1){                                                              \
        __hip_atomic_store(bar_cnt, 0, __ATOMIC_RELAXED, __HIP_MEMORY_SCOPE_AGENT);   \
        __hip_atomic_fetch_add(bar_gen, 1, __ATOMIC_RELEASE,                          \
                               __HIP_MEMORY_SCOPE_AGENT);                             \
      } else {                                                                        \
        while (__hip_atomic_load(bar_gen, __ATOMIC_ACQUIRE,                           \
                                 __HIP_MEMORY_SCOPE_AGENT) < bphase)                  \
          __builtin_amdgcn_s_sleep(2);                                                \
      }                                                                               \
    }                                                                                 \
    __syncthreads();                                                                  \
  } while(0)

__global__ __launch_bounds__(BLK) void wf_kernel(
    const float* __restrict__ y,      const float* __restrict__ samples,
    const float* __restrict__ emb,    const float* __restrict__ condW,
    const float* __restrict__ ln_w,   const float* __restrict__ ln_b,
    const float* __restrict__ kv_w,   const float* __restrict__ kv_b,
    const float* __restrict__ q_w,    const float* __restrict__ q_b,
    const float* __restrict__ o_w,    const float* __restrict__ o_b,
    const float* __restrict__ fln_w,  const float* __restrict__ fln_b,
    const float* __restrict__ ff_w1,  const float* __restrict__ ff_b1,
    const float* __restrict__ ff_w2,  const float* __restrict__ ff_b2,
    const float* __restrict__ head_r, const float* __restrict__ last_w,
    const float* __restrict__ last_b,
    int* __restrict__ outp, float* __restrict__ ws)
{
  const int tid  = threadIdx.x;
  const int b    = blockIdx.x;
  const int lane = tid & 63;
  const int wid  = tid >> 6;

  int* bar_cnt = (int*)ws;        // zeroed by hipMemsetAsync before launch
  int* bar_gen = (int*)ws + 32;   // separate cacheline-ish
  float* embt   = ws + 128;                    // 256*512
  float* ycond  = embt  + NCLS*DM;             // 512*512  [t][d]
  float* kvc    = ycond + TT*DM;               // 8*32*1024 circular KV cache
  float* hq     = kvc   + LAYERS*WIN*2*DM;     // 512
  float* xbuf   = hq    + DM;                  // 512 residual out of layer
  float* xc2b   = xbuf  + DM;                  // 512 post-attention residual
  float* hbuf   = xc2b  + DM;                  // 2048 FFN hidden
  float* logitb = hbuf  + DFF;                 // 256

  __shared__ __align__(16) float s_xc[DM];
  __shared__ __align__(16) float s_tmp[DM];
  __shared__ __align__(16) float s_out[DM];
  __shared__ float s_attn[NH*WIN];
  __shared__ float s_red[8];
  __shared__ int   s_ired[4];

  int bphase = 0;
  const int gtid = b*BLK + tid;

  // ---- one-time precompute: emb_t = tanh(emb); ycond[t][d] = sum_m condW[d][m]*y[m][t]
  for (int i = gtid; i < NCLS*DM; i += GRID*BLK) embt[i] = tanhf(emb[i]);
  for (int i = gtid; i < TT*DM; i += GRID*BLK){
    int t = i >> 9, d = i & 511;
    float acc = 0.f;
    for (int m = 0; m < MEL; m++) acc += condW[d*MEL + m] * y[m*TT + t];
    ycond[i] = acc;
  }
  GBAR();

  int cur_idx = NCLS/2 - 1;      // x0 = emb_t[127]
  const float scale = 0.125f;    // 1/sqrt(64)

  for (int t = 0; t < TT; t++){
    const float* cond = ycond + t*DM;
    const int slot = t & (WIN-1);
    const int wlo  = (t >= WIN-1) ? 0 : (WIN-1 - t);

    for (int l = 0; l < LAYERS; l++){
      // ================= stage 1: xc, LN (redundant), KV+Q matvec =================
      for (int e = tid; e < DM; e += BLK){
        float xv = (l == 0) ? embt[cur_idx*DM + e] : xbuf[e];
        s_xc[e] = cond[e] + xv;
      }
      __syncthreads();
      {
        float part = s_xc[tid] + s_xc[tid + BLK];
        float wsum = wredsum(part);
        if (lane == 0) s_red[wid] = wsum;
        __syncthreads();
        float mu = (s_red[0]+s_red[1]+s_red[2]+s_red[3]) * (1.0f/DM);
        float d0 = s_xc[tid] - mu, d1 = s_xc[tid+BLK] - mu;
        float vs = wredsum(d0*d0 + d1*d1);
        __syncthreads();
        if (lane == 0) s_red[wid] = vs;
        __syncthreads();
        float var  = (s_red[0]+s_red[1]+s_red[2]+s_red[3]) * (1.0f/DM);
        float rsig = 1.0f / sqrtf(var + 1e-5f);
        const float* lw = ln_w + l*DM; const float* lb = ln_b + l*DM;
        for (int e = tid; e < DM; e += BLK)
          s_tmp[e] = (s_xc[e] - mu)*rsig*lw[e] + lb[e];
      }
      __syncthreads();
      {
        const float* kw = kv_w + (size_t)l*2*DM*DM;
        const float* kb = kv_b + l*2*DM;
        const float* qw = q_w  + (size_t)l*DM*DM;
        const float* qb = q_b  + l*DM;
        float* cacheRow = kvc + (l*WIN + slot)*2*DM;   // token t lives at slot t%W
        const int rbase = b*24;                         // 1536 rows / 64 blocks
        for (int j = wid; j < 24; j += 4){
          int r = rbase + j;
          if (r < 2*DM){
            float dv = dot512(kw + (size_t)r*DM, s_tmp, lane) + kb[r];
            if (lane == 0) cacheRow[r] = dv;
          } else {
            int rq = r - 2*DM;
            float dv = dot512(qw + (size_t)rq*DM, s_tmp, lane) + qb[rq];
            if (lane == 0) hq[rq] = dv;
          }
        }
      }
      GBAR();

      // ======= stage 2: attention (redundant per block) + O matvec (distributed) =======
      {
        // scores: tid -> (h = tid>>5, w = tid&31); softmax over the 32-lane half-wave
        int h = tid >> 5, wslot = tid & 31;
        float s;
        if (wslot >= wlo){
          int c = (t + 1 + wslot) & (WIN-1);            // circular slot of token t-31+w
          const float* kk = kvc + (l*WIN + c)*2*DM + h*DHD;
          const float* rr = head_r + (size_t)((l*WIN + wslot)*NH + h)*DHD;
          const float* qq = hq + h*DHD;
          float acc = 0.f;
          for (int d4 = 0; d4 < DHD; d4 += 4){
            float4 kv4 = *(const float4*)(kk + d4);
            float4 rv  = *(const float4*)(rr + d4);
            float4 qv  = *(const float4*)(qq + d4);
            acc += (kv4.x+rv.x)*qv.x + (kv4.y+rv.y)*qv.y
                 + (kv4.z+rv.z)*qv.z + (kv4.w+rv.w)*qv.w;
          }
          s = acc * scale;
        } else s = -INFINITY;
        float m = s;
#pragma unroll
        for (int mm = 16; mm >= 1; mm >>= 1) m = fmaxf(m, __shfl_xor(m, mm, 64));
        float p = (wslot >= wlo) ? expf(s - m) : 0.f;
        float den = p;
#pragma unroll
        for (int mm = 16; mm >= 1; mm >>= 1) den += __shfl_xor(den, mm, 64);
        s_attn[tid] = p / den;
      }
      __syncthreads();
      {
        // out[col] = sum_w attn[h(col),w] * v[c(w)][col]   (redundant per block)
        for (int cb = 0; cb < 2; cb++){
          int col = tid + cb*BLK;
          int h = col >> 6;
          float acc = 0.f;
          for (int wslot = wlo; wslot < WIN; wslot++){
            int c = (t + 1 + wslot) & (WIN-1);
            acc += s_attn[h*WIN + wslot] * kvc[(l*WIN + c)*2*DM + DM + col];
          }
          s_out[col] = acc;
        }
      }
      __syncthreads();
      {
        const float* ow = o_w + (size_t)l*DM*DM;
        const float* ob = o_b + l*DM;
        const int rbase = b*8;                          // 512 rows / 64 blocks
        for (int j = wid; j < 8; j += 4){
          int r = rbase + j;
          float dv = dot512(ow + (size_t)r*DM, s_out, lane) + ob[r] + s_xc[r];
          if (lane == 0) xc2b[r] = dv;
        }
      }
      GBAR();

      // ================= stage 3: LN2 (redundant) + FFN1 matvec + gelu =================
      for (int e = tid; e < DM; e += BLK) s_xc[e] = xc2b[e];
      __syncthreads();
      {
        float part = s_xc[tid] + s_xc[tid + BLK];
        float wsum = wredsum(part);
        if (lane == 0) s_red[wid] = wsum;
        __syncthreads();
        float mu = (s_red[0]+s_red[1]+s_red[2]+s_red[3]) * (1.0f/DM);
        float d0 = s_xc[tid] - mu, d1 = s_xc[tid+BLK] - mu;
        float vs = wredsum(d0*d0 + d1*d1);
        __syncthreads();
        if (lane == 0) s_red[wid] = vs;
        __syncthreads();
        float var  = (s_red[0]+s_red[1]+s_red[2]+s_red[3]) * (1.0f/DM);
        float rsig = 1.0f / sqrtf(var + 1e-5f);
        const float* fw = fln_w + l*DM; const float* fb = fln_b + l*DM;
        for (int e = tid; e < DM; e += BLK)
          s_tmp[e] = (s_xc[e] - mu)*rsig*fw[e] + fb[e];
      }
      __syncthreads();
      {
        const float* w1 = ff_w1 + (size_t)l*DFF*DM;
        const float* b1 = ff_b1 + l*DFF;
        const int rbase = b*32;                         // 2048 rows / 64 blocks
        for (int j = wid; j < 32; j += 4){
          int r = rbase + j;
          float dv = dot512(w1 + (size_t)r*DM, s_tmp, lane) + b1[r];
          if (lane == 0) hbuf[r] = gelu_tanh(dv);
        }
      }
      GBAR();

      // ================= stage 4: FFN2 matvec (dot-2048) + residual =================
      {
        const float* w2 = ff_w2 + (size_t)l*DM*DFF;
        const float* b2 = ff_b2 + l*DM;
        const int rbase = b*8;
        for (int j = wid; j < 8; j += 4){
          int r = rbase + j;
          const float* wrow = w2 + (size_t)r*DFF;
          float p = 0.f;
          for (int ck = 0; ck < DFF; ck += 256){
            float4 a  = *(const float4*)(wrow + ck + 4*lane);
            float4 hv = *(const float4*)(hbuf + ck + 4*lane);
            p += a.x*hv.x + a.y*hv.y + a.z*hv.z + a.w*hv.w;
          }
          float dv = wredsum(p);
          if (lane == 0) xbuf[r] = dv + b2[r] + s_xc[r];   // s_xc holds xc2
        }
      }
      GBAR();
    } // layers

    // ================= head: logits =================
    {
      int r = b*4 + wid;                                // 256 rows / 64 blocks / 4 waves
      const float* wrow = last_w + (size_t)r*DM;
      float4 a0 = *(const float4*)(wrow + 4*lane);
      float4 a1 = *(const float4*)(wrow + 256 + 4*lane);
      float4 v0 = *(const float4*)(xbuf + 4*lane);
      float4 v1 = *(const float4*)(xbuf + 256 + 4*lane);
      float p = a0.x*v0.x + a0.y*v0.y + a0.z*v0.z + a0.w*v0.w
              + a1.x*v1.x + a1.y*v1.y + a1.z*v1.z + a1.w*v1.w;
      float dv = wredsum(p);
      if (lane == 0) logitb[r] = dv + last_b[r];
    }
    GBAR();

    // ===== sampling: softmax -> cumsum -> first cum>u  (redundant per block, no barrier) =====
    {
      float u  = samples[t];
      float li = logitb[tid];
      float mx = wredmax(li);
      if (lane == 0) s_red[wid] = mx;
      __syncthreads();
      mx = fmaxf(fmaxf(s_red[0], s_red[1]), fmaxf(s_red[2], s_red[3]));
      float p  = expf(li - mx);
      float sm = wredsum(p);
      __syncthreads();
      if (lane == 0) s_red[wid] = sm;
      __syncthreads();
      float den = s_red[0]+s_red[1]+s_red[2]+s_red[3];
      float q = p / den;                                 // normalize first (matches ref)
      float x = q;                                       // inclusive wave scan
#pragma unroll
      for (int off = 1; off < 64; off <<= 1){
        float n = __shfl_up(x, off, 64);
        if (lane >= off) x += n;
      }
      __syncthreads();
      if (lane == 63) s_red[wid] = x;
      __syncthreads();
      float offs = 0.f;
      for (int j2 = 0; j2 < wid; j2++) offs += s_red[j2];
      float cum = x + offs;
      unsigned long long bal = __ballot(cum > u);
      int first = (bal != 0ULL) ? (__ffsll(bal) - 1) : 9999;
      if (lane == 0) s_ired[wid] = (first < 9999) ? (wid*64 + first) : 9999;
      __syncthreads();
      int idx = min(min(s_ired[0], s_ired[1]), min(s_ired[2], s_ired[3]));
      if (idx == 9999) idx = 0;                          // argmax of all-False = 0
      cur_idx = idx;
      if (b == 0 && tid == 0) outp[t] = idx;
      __syncthreads();
    }
  } // t
}

extern "C" void kernel_launch(void* const* d_in, const int* in_sizes, int n_in,
                              void* d_out, int out_size, void* d_ws, size_t ws_size,
                              hipStream_t stream)
{
  (void)in_sizes; (void)n_in; (void)out_size; (void)ws_size;
  // zero barrier counters (d_ws is poisoned 0xAA before every launch)
  hipMemsetAsync(d_ws, 0, 512, stream);

  const float* y      = (const float*)d_in[0];
  const float* samp   = (const float*)d_in[1];
  const float* emb    = (const float*)d_in[2];
  const float* condW  = (const float*)d_in[3];
  const float* ln_w   = (const float*)d_in[4];
  const float* ln_b   = (const float*)d_in[5];
  const float* kv_w   = (const float*)d_in[6];
  const float* kv_b   = (const float*)d_in[7];
  const float* q_w    = (const float*)d_in[8];
  const float* q_b    = (const float*)d_in[9];
  const float* o_w    = (const float*)d_in[10];
  const float* o_b    = (const float*)d_in[11];
  const float* fln_w  = (const float*)d_in[12];
  const float* fln_b  = (const float*)d_in[13];
  const float* ff_w1  = (const float*)d_in[14];
  const float* ff_b1  = (const float*)d_in[15];
  const float* ff_w2  = (const float*)d_in[16];
  const float* ff_b2  = (const float*)d_in[17];
  const float* head_r = (const float*)d_in[18];
  const float* last_w = (const float*)d_in[19];
  const float* last_b = (const float*)d_in[20];

  wf_kernel<<<GRID, BLK, 0, stream>>>(y, samp, emb, condW, ln_w, ln_b, kv_w, kv_b,
                                      q_w, q_b, o_w, o_b, fln_w, fln_b,
                                      ff_w1, ff_b1, ff_w2, ff_b2, head_r,
                                      last_w, last_b,
                                      (int*)d_out, (float*)d_ws);
}

// Round 2
// 148984.692 us; speedup vs baseline: 1.4148x; 1.4148x over previous
//
#include <hip/hip_runtime.h>
#include <math.h>

// ---- model dims ----
#define LAYERS 8
#define WIN    32
#define NH     8
#define DHD    64
#define DM     512
#define DFF    2048
#define NCLS   256
#define MEL    80
#define TT     512

// ---- persistent kernel: 64 blocks x 256 threads ----
#define GRID   64
#define BLK    256
#define FSTRIDE 4   // flags padded to 16B

// ---- wave=64 reductions ----
__device__ inline float wredsum(float v){
#pragma unroll
  for (int m = 32; m >= 1; m >>= 1) v += __shfl_xor(v, m, 64);
  return v;
}
__device__ inline float wredmax(float v){
#pragma unroll
  for (int m = 32; m >= 1; m >>= 1) v = fmaxf(v, __shfl_xor(v, m, 64));
  return v;
}

// ---- coherent (sc-bit) scalar/vector comm ops: relaxed agent scope => no cache
// maintenance instructions, data goes to/from the cross-XCD coherence point.
__device__ inline float ld_sc(float* p){
  return __hip_atomic_load(p, __ATOMIC_RELAXED, __HIP_MEMORY_SCOPE_AGENT);
}
__device__ inline void st_sc(float* p, float v){
  __hip_atomic_store(p, v, __ATOMIC_RELAXED, __HIP_MEMORY_SCOPE_AGENT);
}
__device__ inline float2 ld_sc2(float* p){
  unsigned long long u = __hip_atomic_load((unsigned long long*)p,
                                           __ATOMIC_RELAXED, __HIP_MEMORY_SCOPE_AGENT);
  union { unsigned long long u; float2 f; } cv; cv.u = u; return cv.f;
}

// dot(wrow[0:512], vec512_in_LDS) across one wave
__device__ inline float dot512(const float* __restrict__ wrow, const float* vec, int lane){
  float4 a0 = *(const float4*)(wrow + 4*lane);
  float4 a1 = *(const float4*)(wrow + 256 + 4*lane);
  float4 b0 = *(const float4*)(vec + 4*lane);
  float4 b1 = *(const float4*)(vec + 256 + 4*lane);
  float p = a0.x*b0.x + a0.y*b0.y + a0.z*b0.z + a0.w*b0.w
          + a1.x*b1.x + a1.y*b1.y + a1.z*b1.z + a1.w*b1.w;
  return wredsum(p);
}

__device__ inline float gelu_tanh(float x){
  float x3 = x*x*x;
  return 0.5f*x*(1.0f + tanhf(0.7978845608028654f*(x + 0.044715f*x3)));
}

// flag-array barrier: no RMW contention, no acquire/release cache ops.
// __syncthreads() drains each thread's vmcnt (sc-stores reach coherence point)
// before tid0 publishes the phase.
__device__ inline void gbar(int* flags, int b, int& ph, int tid){
  ph++;
  __syncthreads();
  if (tid == 0)
    __hip_atomic_store(flags + b*FSTRIDE, ph, __ATOMIC_RELAXED, __HIP_MEMORY_SCOPE_AGENT);
  if (tid < GRID){
    while (__hip_atomic_load(flags + tid*FSTRIDE, __ATOMIC_RELAXED,
                             __HIP_MEMORY_SCOPE_AGENT) < ph)
      __builtin_amdgcn_s_sleep(1);
  }
  asm volatile("" ::: "memory");
  __syncthreads();
}

__global__ __launch_bounds__(BLK, 1) void wf_kernel(
    const float* __restrict__ y,      const float* __restrict__ samples,
    const float* __restrict__ emb,    const float* __restrict__ condW,
    const float* __restrict__ ln_w,   const float* __restrict__ ln_b,
    const float* __restrict__ kv_w,   const float* __restrict__ kv_b,
    const float* __restrict__ q_w,    const float* __restrict__ q_b,
    const float* __restrict__ o_w,    const float* __restrict__ o_b,
    const float* __restrict__ fln_w,  const float* __restrict__ fln_b,
    const float* __restrict__ ff_w1,  const float* __restrict__ ff_b1,
    const float* __restrict__ ff_w2,  const float* __restrict__ ff_b2,
    const float* __restrict__ head_r, const float* __restrict__ last_w,
    const float* __restrict__ last_b,
    int* __restrict__ outp, float* __restrict__ ws)
{
  const int tid  = threadIdx.x;
  const int b    = blockIdx.x;
  const int lane = tid & 63;
  const int wid  = tid >> 6;

  int*   flags  = (int*)ws;                    // 256 ints (1 KB), zeroed by memset
  float* embt   = ws + 512;                    // 256*512
  float* ycond  = embt  + NCLS*DM;             // 512*512 [t][d]
  float* kvc    = ycond + TT*DM;               // 8*32*1024 circular KV cache
  float* hq     = kvc   + LAYERS*WIN*2*DM;     // 512
  float* xbuf   = hq    + DM;                  // 512
  float* xc2b   = xbuf  + DM;                  // 512
  float* hbuf   = xc2b  + DM;                  // 2048
  float* logitb = hbuf  + DFF;                 // 256

  __shared__ __align__(16) float s_xc[DM];
  __shared__ __align__(16) float s_tmp[DM];
  __shared__ __align__(16) float s_out[DM];
  __shared__ __align__(16) float s_q[DM];
  __shared__ __align__(16) float s_h[DFF];
  __shared__ float s_attn[NH*WIN];
  __shared__ float s_red[8];
  __shared__ int   s_ired[4];
  __shared__ float s_y[MEL];

  int ph = 0;

  // ======== one-time precompute ========
  // emb_t = tanh(emb)
  {
    const int gtid = b*BLK + tid;
    for (int i = gtid; i < NCLS*DM; i += GRID*BLK) st_sc(embt + i, tanhf(emb[i]));
  }
  // ycond[t][d] = sum_m condW[d][m] * y[m][t]; block b owns 8 consecutive t
  for (int k = 0; k < 8; k++){
    int t0 = b*8 + k;
    if (tid < MEL) s_y[tid] = y[tid*TT + t0];
    __syncthreads();
    for (int dd = tid; dd < DM; dd += BLK){
      const float* cw = condW + dd*MEL;
      float acc = 0.f;
#pragma unroll
      for (int m4 = 0; m4 < MEL; m4 += 4){
        float4 c4 = *(const float4*)(cw + m4);
        acc += c4.x*s_y[m4] + c4.y*s_y[m4+1] + c4.z*s_y[m4+2] + c4.w*s_y[m4+3];
      }
      st_sc(ycond + t0*DM + dd, acc);
    }
    __syncthreads();
  }
  gbar(flags, b, ph, tid);

  int cur_idx = NCLS/2 - 1;
  const float scale = 0.125f;

  for (int t = 0; t < TT; t++){
    float* cond = ycond + t*DM;
    const int slot = t & (WIN-1);
    const int wlo  = (t >= WIN-1) ? 0 : (WIN-1 - t);

    for (int l = 0; l < LAYERS; l++){
      // ========== stage 1: xc = cond + x, LN (redundant), KV+Q matvec ==========
      {
        float2 xv = (l == 0) ? *(const float2*)(embt + cur_idx*DM + 2*tid)
                             : ld_sc2(xbuf + 2*tid);
        float2 cv = *(const float2*)(cond + 2*tid);
        s_xc[2*tid]   = cv.x + xv.x;
        s_xc[2*tid+1] = cv.y + xv.y;
      }
      __syncthreads();
      {
        float part = s_xc[tid] + s_xc[tid + BLK];
        float wsum = wredsum(part);
        if (lane == 0) s_red[wid] = wsum;
        __syncthreads();
        float mu = (s_red[0]+s_red[1]+s_red[2]+s_red[3]) * (1.0f/DM);
        float d0 = s_xc[tid] - mu, d1 = s_xc[tid+BLK] - mu;
        float vs = wredsum(d0*d0 + d1*d1);
        __syncthreads();
        if (lane == 0) s_red[wid] = vs;
        __syncthreads();
        float var  = (s_red[0]+s_red[1]+s_red[2]+s_red[3]) * (1.0f/DM);
        float rsig = 1.0f / sqrtf(var + 1e-5f);
        const float* lw = ln_w + l*DM; const float* lb = ln_b + l*DM;
        s_tmp[tid]     = (s_xc[tid]     - mu)*rsig*lw[tid]     + lb[tid];
        s_tmp[tid+BLK] = (s_xc[tid+BLK] - mu)*rsig*lw[tid+BLK] + lb[tid+BLK];
      }
      __syncthreads();
      {
        const float* kw = kv_w + (size_t)l*2*DM*DM;
        const float* kb = kv_b + l*2*DM;
        const float* qw = q_w  + (size_t)l*DM*DM;
        const float* qb = q_b  + l*DM;
        float* cacheRow = kvc + ((size_t)(l*WIN + slot) << 10);
#pragma unroll
        for (int jj = 0; jj < 6; jj++){
          int r = b*24 + wid*6 + jj;
          if (r < 2*DM){
            float dv = dot512(kw + (size_t)r*DM, s_tmp, lane) + kb[r];
            if (lane == 0) st_sc(cacheRow + r, dv);
          } else {
            int rq = r - 2*DM;
            float dv = dot512(qw + (size_t)rq*DM, s_tmp, lane) + qb[rq];
            if (lane == 0) st_sc(hq + rq, dv);
          }
        }
      }
      gbar(flags, b, ph, tid);

      // ========== stage 2: attention (redundant) + O matvec (distributed) ==========
      {
        float2 qv = ld_sc2(hq + 2*tid);
        s_q[2*tid] = qv.x; s_q[2*tid+1] = qv.y;
      }
      __syncthreads();
      {
        int h = tid >> 5, w = tid & 31;
        int c = (t + 1 + w) & (WIN-1);
        float* kk = kvc + ((size_t)(l*WIN + c) << 10) + h*DHD;
        const float* rr = head_r + ((size_t)((l*WIN + w)*NH + h) << 6);
        float acc = 0.f;
#pragma unroll
        for (int i = 0; i < DHD; i += 2){
          float2 kv2 = ld_sc2(kk + i);
          float2 rv  = *(const float2*)(rr + i);
          acc += (kv2.x + rv.x)*s_q[h*DHD + i] + (kv2.y + rv.y)*s_q[h*DHD + i + 1];
        }
        float s = (w >= wlo) ? acc*scale : -INFINITY;
        float m = s;
#pragma unroll
        for (int mm = 16; mm >= 1; mm >>= 1) m = fmaxf(m, __shfl_xor(m, mm, 64));
        float p = (w >= wlo) ? expf(s - m) : 0.f;
        float den = p;
#pragma unroll
        for (int mm = 16; mm >= 1; mm >>= 1) den += __shfl_xor(den, mm, 64);
        s_attn[tid] = p / den;
      }
      __syncthreads();
      {
        int h2 = tid >> 5;
        float a0 = 0.f, a1 = 0.f;
#pragma unroll
        for (int w2 = 0; w2 < WIN; w2++){
          float p = s_attn[h2*WIN + w2];
          int c = (t + 1 + w2) & (WIN-1);
          float2 vv = ld_sc2(kvc + ((size_t)(l*WIN + c) << 10) + DM + 2*tid);
          a0 += p*vv.x; a1 += p*vv.y;
        }
        s_out[2*tid] = a0; s_out[2*tid+1] = a1;
      }
      __syncthreads();
      {
        const float* ow = o_w + (size_t)l*DM*DM;
        const float* ob = o_b + l*DM;
#pragma unroll
        for (int jj = 0; jj < 2; jj++){
          int r = b*8 + wid*2 + jj;
          float dv = dot512(ow + (size_t)r*DM, s_out, lane) + ob[r] + s_xc[r];
          if (lane == 0) st_sc(xc2b + r, dv);
        }
      }
      gbar(flags, b, ph, tid);

      // ========== stage 3: LN2 (redundant) + FFN1 matvec + gelu ==========
      {
        float2 xv = ld_sc2(xc2b + 2*tid);
        s_xc[2*tid] = xv.x; s_xc[2*tid+1] = xv.y;
      }
      __syncthreads();
      {
        float part = s_xc[tid] + s_xc[tid + BLK];
        float wsum = wredsum(part);
        if (lane == 0) s_red[wid] = wsum;
        __syncthreads();
        float mu = (s_red[0]+s_red[1]+s_red[2]+s_red[3]) * (1.0f/DM);
        float d0 = s_xc[tid] - mu, d1 = s_xc[tid+BLK] - mu;
        float vs = wredsum(d0*d0 + d1*d1);
        __syncthreads();
        if (lane == 0) s_red[wid] = vs;
        __syncthreads();
        float var  = (s_red[0]+s_red[1]+s_red[2]+s_red[3]) * (1.0f/DM);
        float rsig = 1.0f / sqrtf(var + 1e-5f);
        const float* fw = fln_w + l*DM; const float* fb = fln_b + l*DM;
        s_tmp[tid]     = (s_xc[tid]     - mu)*rsig*fw[tid]     + fb[tid];
        s_tmp[tid+BLK] = (s_xc[tid+BLK] - mu)*rsig*fw[tid+BLK] + fb[tid+BLK];
      }
      __syncthreads();
      {
        const float* w1 = ff_w1 + (size_t)l*DFF*DM;
        const float* b1 = ff_b1 + l*DFF;
#pragma unroll
        for (int jj = 0; jj < 8; jj++){
          int r = b*32 + wid*8 + jj;
          float dv = dot512(w1 + (size_t)r*DM, s_tmp, lane) + b1[r];
          if (lane == 0) st_sc(hbuf + r, gelu_tanh(dv));
        }
      }
      gbar(flags, b, ph, tid);

      // ========== stage 4: FFN2 matvec (dot-2048 from LDS) + residual ==========
#pragma unroll
      for (int k2 = 0; k2 < 4; k2++){
        float2 hv = ld_sc2(hbuf + k2*512 + 2*tid);
        s_h[k2*512 + 2*tid] = hv.x; s_h[k2*512 + 2*tid + 1] = hv.y;
      }
      __syncthreads();
      {
        const float* w2p = ff_w2 + (size_t)l*DM*DFF;
        const float* b2p = ff_b2 + l*DM;
#pragma unroll
        for (int jj = 0; jj < 2; jj++){
          int r = b*8 + wid*2 + jj;
          const float* wrow = w2p + (size_t)r*DFF;
          float p = 0.f;
#pragma unroll
          for (int ck = 0; ck < 8; ck++){
            float4 a  = *(const float4*)(wrow + ck*256 + 4*lane);
            float4 hv = *(const float4*)(s_h  + ck*256 + 4*lane);
            p += a.x*hv.x + a.y*hv.y + a.z*hv.z + a.w*hv.w;
          }
          float dv = wredsum(p);
          if (lane == 0) st_sc(xbuf + r, dv + b2p[r] + s_xc[r]);  // s_xc holds xc2
        }
      }
      gbar(flags, b, ph, tid);
    } // layers

    // ========== head: logits ==========
    {
      float2 xv = ld_sc2(xbuf + 2*tid);
      s_tmp[2*tid] = xv.x; s_tmp[2*tid+1] = xv.y;
    }
    __syncthreads();
    {
      int r = b*4 + wid;
      float dv = dot512(last_w + (size_t)r*DM, s_tmp, lane) + last_b[r];
      if (lane == 0) st_sc(logitb + r, dv);
    }
    gbar(flags, b, ph, tid);

    // ===== sampling (redundant per block; deterministic; no barrier needed) =====
    {
      float u  = samples[t];
      float li = ld_sc(logitb + tid);
      float mx = wredmax(li);
      if (lane == 0) s_red[wid] = mx;
      __syncthreads();
      mx = fmaxf(fmaxf(s_red[0], s_red[1]), fmaxf(s_red[2], s_red[3]));
      float p  = expf(li - mx);
      float sm = wredsum(p);
      __syncthreads();
      if (lane == 0) s_red[wid] = sm;
      __syncthreads();
      float den = s_red[0]+s_red[1]+s_red[2]+s_red[3];
      float q = p / den;
      float x = q;
#pragma unroll
      for (int off = 1; off < 64; off <<= 1){
        float n = __shfl_up(x, off, 64);
        if (lane >= off) x += n;
      }
      __syncthreads();
      if (lane == 63) s_red[wid] = x;
      __syncthreads();
      float offs = 0.f;
      for (int j2 = 0; j2 < wid; j2++) offs += s_red[j2];
      float cum = x + offs;
      unsigned long long bal = __ballot(cum > u);
      int first = (bal != 0ULL) ? (__ffsll(bal) - 1) : 9999;
      if (lane == 0) s_ired[wid] = (first < 9999) ? (wid*64 + first) : 9999;
      __syncthreads();
      int idx = min(min(s_ired[0], s_ired[1]), min(s_ired[2], s_ired[3]));
      if (idx == 9999) idx = 0;
      cur_idx = idx;
      if (b == 0 && tid == 0) outp[t] = idx;
      __syncthreads();
    }
  } // t
}

extern "C" void kernel_launch(void* const* d_in, const int* in_sizes, int n_in,
                              void* d_out, int out_size, void* d_ws, size_t ws_size,
                              hipStream_t stream)
{
  (void)in_sizes; (void)n_in; (void)out_size; (void)ws_size;
  hipMemsetAsync(d_ws, 0, 1024, stream);   // zero barrier flags

  const float* y      = (const float*)d_in[0];
  const float* samp   = (const float*)d_in[1];
  const float* emb    = (const float*)d_in[2];
  const float* condW  = (const float*)d_in[3];
  const float* ln_w   = (const float*)d_in[4];
  const float* ln_b   = (const float*)d_in[5];
  const float* kv_w   = (const float*)d_in[6];
  const float* kv_b   = (const float*)d_in[7];
  const float* q_w    = (const float*)d_in[8];
  const float* q_b    = (const float*)d_in[9];
  const float* o_w    = (const float*)d_in[10];
  const float* o_b    = (const float*)d_in[11];
  const float* fln_w  = (const float*)d_in[12];
  const float* fln_b  = (const float*)d_in[13];
  const float* ff_w1  = (const float*)d_in[14];
  const float* ff_b1  = (const float*)d_in[15];
  const float* ff_w2  = (const float*)d_in[16];
  const float* ff_b2  = (const float*)d_in[17];
  const float* head_r = (const float*)d_in[18];
  const float* last_w = (const float*)d_in[19];
  const float* last_b = (const float*)d_in[20];

  wf_kernel<<<GRID, BLK, 0, stream>>>(y, samp, emb, condW, ln_w, ln_b, kv_w, kv_b,
                                      q_w, q_b, o_w, o_b, fln_w, fln_b,
                                      ff_w1, ff_b1, ff_w2, ff_b2, head_r,
                                      last_w, last_b,
                                      (int*)d_out, (float*)d_ws);
}

// Round 3
// 119256.433 us; speedup vs baseline: 1.7675x; 1.2493x over previous
//
#include <hip/hip_runtime.h>
#include <math.h>

// ---- model dims ----
#define LAYERS 8
#define WIN    32
#define NH     8
#define DHD    64
#define DM     512
#define DFF    2048
#define NCLS   256
#define MEL    80
#define TT     512

// ---- persistent kernel: 256 blocks x 256 threads (1 block/CU) ----
#define GRID   256
#define BLK    256
#define FSTRIDE 16   // ints -> 64 B per flag

// ---- wave=64 reductions ----
__device__ inline float wredsum(float v){
#pragma unroll
  for (int m = 32; m >= 1; m >>= 1) v += __shfl_xor(v, m, 64);
  return v;
}
__device__ inline float wredmax(float v){
#pragma unroll
  for (int m = 32; m >= 1; m >>= 1) v = fmaxf(v, __shfl_xor(v, m, 64));
  return v;
}

// ---- coherent (sc-bit) comm ops: relaxed agent scope, no cache maintenance ----
__device__ inline float ld_sc(float* p){
  return __hip_atomic_load(p, __ATOMIC_RELAXED, __HIP_MEMORY_SCOPE_AGENT);
}
__device__ inline void st_sc(float* p, float v){
  __hip_atomic_store(p, v, __ATOMIC_RELAXED, __HIP_MEMORY_SCOPE_AGENT);
}
__device__ inline float2 ld_sc2(float* p){
  unsigned long long u = __hip_atomic_load((unsigned long long*)p,
                                           __ATOMIC_RELAXED, __HIP_MEMORY_SCOPE_AGENT);
  union { unsigned long long u; float2 f; } cv; cv.u = u; return cv.f;
}

// dot(row512, vec512) across one wave (both may be LDS)
__device__ inline float dot512(const float* w, const float* vec, int lane){
  float4 a0 = *(const float4*)(w + 4*lane);
  float4 a1 = *(const float4*)(w + 256 + 4*lane);
  float4 b0 = *(const float4*)(vec + 4*lane);
  float4 b1 = *(const float4*)(vec + 256 + 4*lane);
  float p = a0.x*b0.x + a0.y*b0.y + a0.z*b0.z + a0.w*b0.w
          + a1.x*b1.x + a1.y*b1.y + a1.z*b1.z + a1.w*b1.w;
  return wredsum(p);
}

__device__ inline float gelu_tanh(float x){
  float x3 = x*x*x;
  return 0.5f*x*(1.0f + tanhf(0.7978845608028654f*(x + 0.044715f*x3)));
}

// ---- split-phase barrier ----
__device__ inline void bar_arrive(int* flags, int b, int ph){
  __syncthreads();   // joins block; implicit vmcnt(0) drains sc data stores
  if (threadIdx.x == 0)
    __hip_atomic_store(flags + b*FSTRIDE, ph, __ATOMIC_RELAXED, __HIP_MEMORY_SCOPE_AGENT);
}
__device__ inline void bar_wait(int* flags, int ph){
  // BLK == GRID: thread i polls block i's flag
  while (__hip_atomic_load(flags + threadIdx.x*FSTRIDE, __ATOMIC_RELAXED,
                           __HIP_MEMORY_SCOPE_AGENT) < ph)
    __builtin_amdgcn_s_sleep(1);
  asm volatile("" ::: "memory");
  __syncthreads();
}

// float4 global->LDS copy (all threads), n4 = count of float4
__device__ inline void pf_copy(const float* __restrict__ g, float* l, int n4){
  const float4* g4 = (const float4*)g;
  float4* l4 = (float4*)l;
#pragma unroll 4
  for (int i = threadIdx.x; i < n4; i += BLK) l4[i] = g4[i];
}

// prefetch this block's kvq rows (6) + o_w rows (2) for layer l into s_wA
__device__ inline void pf_kvq_ow(const float* kv_w, const float* q_w, const float* o_w,
                                 int l, int b, float* s_wA){
  int r0 = b*6;
  int nkv = 1024 - r0; nkv = nkv < 0 ? 0 : (nkv > 6 ? 6 : nkv);
  if (nkv > 0)
    pf_copy(kv_w + ((size_t)l*1024 + r0)*DM, s_wA, nkv*128);
  if (nkv < 6)
    pf_copy(q_w + ((size_t)l*512 + (r0 + nkv - 1024))*DM, s_wA + nkv*DM, (6-nkv)*128);
  pf_copy(o_w + ((size_t)l*512 + b*2)*DM, s_wA + 6*DM, 2*128);
}

__global__ __launch_bounds__(BLK, 1) void wf_kernel(
    const float* __restrict__ y,      const float* __restrict__ samples,
    const float* __restrict__ emb,    const float* __restrict__ condW,
    const float* __restrict__ ln_w,   const float* __restrict__ ln_b,
    const float* __restrict__ kv_w,   const float* __restrict__ kv_b,
    const float* __restrict__ q_w,    const float* __restrict__ q_b,
    const float* __restrict__ o_w,    const float* __restrict__ o_b,
    const float* __restrict__ fln_w,  const float* __restrict__ fln_b,
    const float* __restrict__ ff_w1,  const float* __restrict__ ff_b1,
    const float* __restrict__ ff_w2,  const float* __restrict__ ff_b2,
    const float* __restrict__ head_r, const float* __restrict__ last_w,
    const float* __restrict__ last_b,
    int* __restrict__ outp, float* __restrict__ ws)
{
  const int tid  = threadIdx.x;
  const int b    = blockIdx.x;
  const int lane = tid & 63;
  const int wid  = tid >> 6;

  int*   flags  = (int*)ws;                    // 256*16 ints = 16 KB, zeroed
  float* embt   = ws + 4096;                   // 256*512
  float* ycond  = embt  + NCLS*DM;             // 512*512 [t][d]
  float* kvc    = ycond + TT*DM;               // 8*32*1024 circular KV cache
  float* hq     = kvc   + LAYERS*WIN*2*DM;     // 512
  float* xbuf   = hq    + DM;                  // 512
  float* xc2b   = xbuf  + DM;                  // 512
  float* hbuf   = xc2b  + DM;                  // 2048
  float* logitb = hbuf  + DFF;                 // 256

  __shared__ __align__(16) float s_xc[DM];
  __shared__ __align__(16) float s_tmp[DM];
  __shared__ __align__(16) float s_out[DM];
  __shared__ __align__(16) float s_q[DM];
  __shared__ __align__(16) float s_h[DFF];
  __shared__ __align__(16) float s_wA[8*DM];    // kvq rows [0..6), o_w rows [6..8)
  __shared__ __align__(16) float s_wB[8*DM];    // ff1 8 rows | ff2 2x2048 | last_w row
  __shared__ float s_attn[NH*WIN];
  __shared__ float s_red[8];
  __shared__ int   s_ired[4];
  __shared__ float s_y[MEL];

  int ph = 0;

  // ======== one-time precompute ========
  {
    const int gtid = b*BLK + tid;
    for (int i = gtid; i < NCLS*DM; i += GRID*BLK) st_sc(embt + i, tanhf(emb[i]));
  }
  for (int k = 0; k < 2; k++){
    int t0 = b*2 + k;
    if (tid < MEL) s_y[tid] = y[tid*TT + t0];
    __syncthreads();
    for (int dd = tid; dd < DM; dd += BLK){
      const float* cw = condW + dd*MEL;
      float acc = 0.f;
#pragma unroll
      for (int m4 = 0; m4 < MEL; m4 += 4){
        float4 c4 = *(const float4*)(cw + m4);
        acc += c4.x*s_y[m4] + c4.y*s_y[m4+1] + c4.z*s_y[m4+2] + c4.w*s_y[m4+3];
      }
      st_sc(ycond + t0*DM + dd, acc);
    }
    __syncthreads();
  }
  ph++;
  bar_arrive(flags, b, ph);
  pf_kvq_ow(kv_w, q_w, o_w, 0, b, s_wA);  // layer-0 weights for t=0
  bar_wait(flags, ph);

  int cur_idx = NCLS/2 - 1;
  const float scale = 0.125f;

  for (int t = 0; t < TT; t++){
    float* cond = ycond + t*DM;
    const int slot = t & (WIN-1);
    const int wlo  = (t >= WIN-1) ? 0 : (WIN-1 - t);

    for (int l = 0; l < LAYERS; l++){
      // ===== seg1: V-old preload, xc, LN1, KV/Q matvec (LDS weights) =====
      float2 vreg[WIN-1];
#pragma unroll
      for (int w2 = 0; w2 < WIN-1; w2++){
        int c = (t + 1 + w2) & (WIN-1);
        vreg[w2] = ld_sc2(kvc + ((size_t)(l*WIN + c) << 10) + DM + 2*tid);
      }
      {
        float2 xv = (l == 0) ? *(const float2*)(embt + cur_idx*DM + 2*tid)
                             : ld_sc2(xbuf + 2*tid);
        float2 cv = *(const float2*)(cond + 2*tid);
        s_xc[2*tid]   = cv.x + xv.x;
        s_xc[2*tid+1] = cv.y + xv.y;
      }
      __syncthreads();
      {
        float part = s_xc[tid] + s_xc[tid + BLK];
        float wsum = wredsum(part);
        if (lane == 0) s_red[wid] = wsum;
        __syncthreads();
        float mu = (s_red[0]+s_red[1]+s_red[2]+s_red[3]) * (1.0f/DM);
        float d0 = s_xc[tid] - mu, d1 = s_xc[tid+BLK] - mu;
        float vs = wredsum(d0*d0 + d1*d1);
        __syncthreads();
        if (lane == 0) s_red[wid] = vs;
        __syncthreads();
        float var  = (s_red[0]+s_red[1]+s_red[2]+s_red[3]) * (1.0f/DM);
        float rsig = 1.0f / sqrtf(var + 1e-5f);
        const float* lw = ln_w + l*DM; const float* lb = ln_b + l*DM;
        s_tmp[tid]     = (s_xc[tid]     - mu)*rsig*lw[tid]     + lb[tid];
        s_tmp[tid+BLK] = (s_xc[tid+BLK] - mu)*rsig*lw[tid+BLK] + lb[tid+BLK];
      }
      __syncthreads();
      {
        float* cacheRow = kvc + ((size_t)(l*WIN + slot) << 10);
        for (int j = wid; j < 6; j += 4){
          int r = b*6 + j;
          float dv = dot512(s_wA + j*DM, s_tmp, lane);
          if (r < 2*DM){
            dv += kv_b[l*2*DM + r];
            if (lane == 0) st_sc(cacheRow + r, dv);
          } else {
            int rq = r - 2*DM;
            dv += q_b[l*DM + rq];
            if (lane == 0) st_sc(hq + rq, dv);
          }
        }
      }
      ph++;
      bar_arrive(flags, b, ph);
      pf_copy(ff_w1 + (size_t)l*DFF*DM + (size_t)(b*8)*DM, s_wB, 8*128);
      bar_wait(flags, ph);

      // ===== seg2: attention (V from regs) + O matvec (LDS weights) =====
      float2 vfresh;
      {
        float2 qv = ld_sc2(hq + 2*tid);
        s_q[2*tid] = qv.x; s_q[2*tid+1] = qv.y;
        vfresh = ld_sc2(kvc + ((size_t)(l*WIN + slot) << 10) + DM + 2*tid);
      }
      __syncthreads();
      {
        int h = tid >> 5, w = tid & 31;
        int c = (t + 1 + w) & (WIN-1);
        float* kk = kvc + ((size_t)(l*WIN + c) << 10) + h*DHD;
        const float* rr = head_r + ((size_t)((l*WIN + w)*NH + h) << 6);
        float acc = 0.f;
#pragma unroll
        for (int i = 0; i < DHD; i += 2){
          float2 kv2 = ld_sc2(kk + i);
          float2 rv  = *(const float2*)(rr + i);
          acc += (kv2.x + rv.x)*s_q[h*DHD + i] + (kv2.y + rv.y)*s_q[h*DHD + i + 1];
        }
        float s = (w >= wlo) ? acc*scale : -INFINITY;
        float m = s;
#pragma unroll
        for (int mm = 16; mm >= 1; mm >>= 1) m = fmaxf(m, __shfl_xor(m, mm, 64));
        float p = (w >= wlo) ? expf(s - m) : 0.f;
        float den = p;
#pragma unroll
        for (int mm = 16; mm >= 1; mm >>= 1) den += __shfl_xor(den, mm, 64);
        s_attn[tid] = p / den;
      }
      __syncthreads();
      {
        int h2 = tid >> 5;
        float a0 = 0.f, a1 = 0.f;
#pragma unroll
        for (int w2 = 0; w2 < WIN-1; w2++){
          float p = s_attn[h2*WIN + w2];
          a0 += p*vreg[w2].x; a1 += p*vreg[w2].y;
        }
        float pl = s_attn[h2*WIN + (WIN-1)];
        a0 += pl*vfresh.x; a1 += pl*vfresh.y;
        s_out[2*tid] = a0; s_out[2*tid+1] = a1;
      }
      __syncthreads();
      {
        for (int jj = wid; jj < 2; jj += 4){
          int r = b*2 + jj;
          float dv = dot512(s_wA + (6+jj)*DM, s_out, lane) + o_b[l*DM + r] + s_xc[r];
          if (lane == 0) st_sc(xc2b + r, dv);
        }
      }
      ph++;
      bar_arrive(flags, b, ph);
      bar_wait(flags, ph);

      // ===== seg3: LN2 + FFN1 matvec (LDS weights) =====
      {
        float2 xv = ld_sc2(xc2b + 2*tid);
        s_xc[2*tid] = xv.x; s_xc[2*tid+1] = xv.y;
      }
      __syncthreads();
      {
        float part = s_xc[tid] + s_xc[tid + BLK];
        float wsum = wredsum(part);
        if (lane == 0) s_red[wid] = wsum;
        __syncthreads();
        float mu = (s_red[0]+s_red[1]+s_red[2]+s_red[3]) * (1.0f/DM);
        float d0 = s_xc[tid] - mu, d1 = s_xc[tid+BLK] - mu;
        float vs = wredsum(d0*d0 + d1*d1);
        __syncthreads();
        if (lane == 0) s_red[wid] = vs;
        __syncthreads();
        float var  = (s_red[0]+s_red[1]+s_red[2]+s_red[3]) * (1.0f/DM);
        float rsig = 1.0f / sqrtf(var + 1e-5f);
        const float* fw = fln_w + l*DM; const float* fb = fln_b + l*DM;
        s_tmp[tid]     = (s_xc[tid]     - mu)*rsig*fw[tid]     + fb[tid];
        s_tmp[tid+BLK] = (s_xc[tid+BLK] - mu)*rsig*fw[tid+BLK] + fb[tid+BLK];
      }
      __syncthreads();
      {
        for (int k2 = 0; k2 < 2; k2++){
          int jj = wid*2 + k2;
          int r = b*8 + jj;
          float dv = dot512(s_wB + jj*DM, s_tmp, lane) + ff_b1[l*DFF + r];
          if (lane == 0) st_sc(hbuf + r, gelu_tanh(dv));
        }
      }
      ph++;
      bar_arrive(flags, b, ph);
      pf_copy(ff_w2 + (size_t)l*DM*DFF + (size_t)(b*2)*DFF, s_wB, 2*512);
      bar_wait(flags, ph);

      // ===== seg4: FFN2 matvec (LDS weights, dot-2048) + residual =====
#pragma unroll
      for (int k2 = 0; k2 < 4; k2++){
        float2 hv = ld_sc2(hbuf + k2*512 + 2*tid);
        s_h[k2*512 + 2*tid] = hv.x; s_h[k2*512 + 2*tid + 1] = hv.y;
      }
      __syncthreads();
      {
        const float* b2p = ff_b2 + l*DM;
        for (int jj = wid; jj < 2; jj += 4){
          int r = b*2 + jj;
          const float* wrow = s_wB + jj*DFF;
          float p = 0.f;
#pragma unroll
          for (int ck = 0; ck < 8; ck++){
            float4 a  = *(const float4*)(wrow + ck*256 + 4*lane);
            float4 hv = *(const float4*)(s_h  + ck*256 + 4*lane);
            p += a.x*hv.x + a.y*hv.y + a.z*hv.z + a.w*hv.w;
          }
          float dv = wredsum(p);
          if (lane == 0) st_sc(xbuf + r, dv + b2p[r] + s_xc[r]);
        }
      }
      ph++;
      bar_arrive(flags, b, ph);
      if (l < LAYERS-1){
        pf_kvq_ow(kv_w, q_w, o_w, l+1, b, s_wA);
      } else {
        pf_kvq_ow(kv_w, q_w, o_w, 0, b, s_wA);          // next step layer 0
        pf_copy(last_w + (size_t)b*DM, s_wB, 128);      // head row
      }
      bar_wait(flags, ph);
    } // layers

    // ===== head: logits (1 row per block, wave0) =====
    {
      float2 xv = ld_sc2(xbuf + 2*tid);
      s_tmp[2*tid] = xv.x; s_tmp[2*tid+1] = xv.y;
    }
    __syncthreads();
    if (wid == 0){
      float dv = dot512(s_wB, s_tmp, lane) + last_b[b];
      if (lane == 0) st_sc(logitb + b, dv);
    }
    ph++;
    bar_arrive(flags, b, ph);
    bar_wait(flags, ph);

    // ===== sampling (redundant per block; deterministic; no barrier) =====
    {
      float u  = samples[t];
      float li = ld_sc(logitb + tid);
      float mx = wredmax(li);
      if (lane == 0) s_red[wid] = mx;
      __syncthreads();
      mx = fmaxf(fmaxf(s_red[0], s_red[1]), fmaxf(s_red[2], s_red[3]));
      float p  = expf(li - mx);
      float sm = wredsum(p);
      __syncthreads();
      if (lane == 0) s_red[wid] = sm;
      __syncthreads();
      float den = s_red[0]+s_red[1]+s_red[2]+s_red[3];
      float q = p / den;
      float x = q;
#pragma unroll
      for (int off = 1; off < 64; off <<= 1){
        float n = __shfl_up(x, off, 64);
        if (lane >= off) x += n;
      }
      __syncthreads();
      if (lane == 63) s_red[wid] = x;
      __syncthreads();
      float offs = 0.f;
      for (int j2 = 0; j2 < wid; j2++) offs += s_red[j2];
      float cum = x + offs;
      unsigned long long bal = __ballot(cum > u);
      int first = (bal != 0ULL) ? (__ffsll(bal) - 1) : 9999;
      if (lane == 0) s_ired[wid] = (first < 9999) ? (wid*64 + first) : 9999;
      __syncthreads();
      int idx = min(min(s_ired[0], s_ired[1]), min(s_ired[2], s_ired[3]));
      if (idx == 9999) idx = 0;
      cur_idx = idx;
      if (b == 0 && tid == 0) outp[t] = idx;
      __syncthreads();
    }
  } // t
}

extern "C" void kernel_launch(void* const* d_in, const int* in_sizes, int n_in,
                              void* d_out, int out_size, void* d_ws, size_t ws_size,
                              hipStream_t stream)
{
  (void)in_sizes; (void)n_in; (void)out_size; (void)ws_size;
  hipMemsetAsync(d_ws, 0, 16384, stream);   // zero barrier flags

  const float* y      = (const float*)d_in[0];
  const float* samp   = (const float*)d_in[1];
  const float* emb    = (const float*)d_in[2];
  const float* condW  = (const float*)d_in[3];
  const float* ln_w   = (const float*)d_in[4];
  const float* ln_b   = (const float*)d_in[5];
  const float* kv_w   = (const float*)d_in[6];
  const float* kv_b   = (const float*)d_in[7];
  const float* q_w    = (const float*)d_in[8];
  const float* q_b    = (const float*)d_in[9];
  const float* o_w    = (const float*)d_in[10];
  const float* o_b    = (const float*)d_in[11];
  const float* fln_w  = (const float*)d_in[12];
  const float* fln_b  = (const float*)d_in[13];
  const float* ff_w1  = (const float*)d_in[14];
  const float* ff_b1  = (const float*)d_in[15];
  const float* ff_w2  = (const float*)d_in[16];
  const float* ff_b2  = (const float*)d_in[17];
  const float* head_r = (const float*)d_in[18];
  const float* last_w = (const float*)d_in[19];
  const float* last_b = (const float*)d_in[20];

  wf_kernel<<<GRID, BLK, 0, stream>>>(y, samp, emb, condW, ln_w, ln_b, kv_w, kv_b,
                                      q_w, q_b, o_w, o_b, fln_w, fln_b,
                                      ff_w1, ff_b1, ff_w2, ff_b2, head_r,
                                      last_w, last_b,
                                      (int*)d_out, (float*)d_ws);
}

// Round 4
// 89148.438 us; speedup vs baseline: 2.3645x; 1.3377x over previous
//
#include <hip/hip_runtime.h>
#include <math.h>

// ---- model dims ----
#define LAYERS 8
#define WIN    32
#define NH     8
#define DHD    64
#define DM     512
#define DFF    2048
#define NCLS   256
#define MEL    80
#define TT     512

// ---- persistent kernel: 256 blocks x 256 threads (1 block/CU) ----
#define GRID   256
#define BLK    256
#define FSTRIDE 16   // ints -> 64 B per flag

// ---- wave=64 reductions ----
__device__ inline float wredsum(float v){
#pragma unroll
  for (int m = 32; m >= 1; m >>= 1) v += __shfl_xor(v, m, 64);
  return v;
}
__device__ inline float wredmax(float v){
#pragma unroll
  for (int m = 32; m >= 1; m >>= 1) v = fmaxf(v, __shfl_xor(v, m, 64));
  return v;
}

// ---- coherent (sc-bit) comm ops: relaxed agent scope, no cache maintenance ----
__device__ inline float ld_sc(float* p){
  return __hip_atomic_load(p, __ATOMIC_RELAXED, __HIP_MEMORY_SCOPE_AGENT);
}
__device__ inline void st_sc(float* p, float v){
  __hip_atomic_store(p, v, __ATOMIC_RELAXED, __HIP_MEMORY_SCOPE_AGENT);
}
__device__ inline float2 ld_sc2(float* p){
  unsigned long long u = __hip_atomic_load((unsigned long long*)p,
                                           __ATOMIC_RELAXED, __HIP_MEMORY_SCOPE_AGENT);
  union { unsigned long long u; float2 f; } cv; cv.u = u; return cv.f;
}

// dot(row512_in_LDS, vec512_in_LDS) across one wave
__device__ inline float dot512(const float* w, const float* vec, int lane){
  float4 a0 = *(const float4*)(w + 4*lane);
  float4 a1 = *(const float4*)(w + 256 + 4*lane);
  float4 b0 = *(const float4*)(vec + 4*lane);
  float4 b1 = *(const float4*)(vec + 256 + 4*lane);
  float p = a0.x*b0.x + a0.y*b0.y + a0.z*b0.z + a0.w*b0.w
          + a1.x*b1.x + a1.y*b1.y + a1.z*b1.z + a1.w*b1.w;
  return wredsum(p);
}

__device__ inline float gelu_tanh(float x){
  float x3 = x*x*x;
  return 0.5f*x*(1.0f + tanhf(0.7978845608028654f*(x + 0.044715f*x3)));
}

// ---- split-phase barrier; only wave0 polls (64 lanes x 4 flags) ----
__device__ inline void bar_arrive(int* flags, int b, int ph){
  __syncthreads();   // drains vmcnt: all sc stores/atomics of this block visible
  if (threadIdx.x == 0)
    __hip_atomic_store(flags + b*FSTRIDE, ph, __ATOMIC_RELAXED, __HIP_MEMORY_SCOPE_AGENT);
}
__device__ inline void bar_wait(int* flags, int ph){
  int tid = threadIdx.x;
  if (tid < 64){
    for (;;){
      int a0 = __hip_atomic_load(flags + tid*FSTRIDE,        __ATOMIC_RELAXED, __HIP_MEMORY_SCOPE_AGENT);
      int a1 = __hip_atomic_load(flags + (tid+64)*FSTRIDE,   __ATOMIC_RELAXED, __HIP_MEMORY_SCOPE_AGENT);
      int a2 = __hip_atomic_load(flags + (tid+128)*FSTRIDE,  __ATOMIC_RELAXED, __HIP_MEMORY_SCOPE_AGENT);
      int a3 = __hip_atomic_load(flags + (tid+192)*FSTRIDE,  __ATOMIC_RELAXED, __HIP_MEMORY_SCOPE_AGENT);
      if (min(min(a0,a1),min(a2,a3)) >= ph) break;
      __builtin_amdgcn_s_sleep(1);
    }
  }
  asm volatile("" ::: "memory");
  __syncthreads();
}

// float4 global->LDS copy (all threads), n4 = count of float4
__device__ inline void pf_copy(const float* __restrict__ g, float* l, int n4){
  const float4* g4 = (const float4*)g;
  float4* l4 = (float4*)l;
#pragma unroll 4
  for (int i = threadIdx.x; i < n4; i += BLK) l4[i] = g4[i];
}

// prefetch this block's 6 kv/q rows for layer l into s_wA (3072 floats)
__device__ inline void pf_kvq(const float* kv_w, const float* q_w, int l, int b, float* s_wA){
  for (int i = threadIdx.x; i < 768; i += BLK){
    int j = i >> 7, off = i & 127;
    int r = b*6 + j;
    float4 v;
    if (r < 2*DM) v = ((const float4*)(kv_w + ((size_t)l*2*DM + r)*DM))[off];
    else          v = ((const float4*)(q_w  + ((size_t)l*DM + (r-2*DM))*DM))[off];
    ((float4*)(s_wA + j*DM))[off] = v;
  }
}

__global__ __launch_bounds__(BLK, 1) void wf_kernel(
    const float* __restrict__ y,      const float* __restrict__ samples,
    const float* __restrict__ emb,    const float* __restrict__ condW,
    const float* __restrict__ ln_w,   const float* __restrict__ ln_b,
    const float* __restrict__ kv_w,   const float* __restrict__ kv_b,
    const float* __restrict__ q_w,    const float* __restrict__ q_b,
    const float* __restrict__ o_w,    const float* __restrict__ o_b,
    const float* __restrict__ fln_w,  const float* __restrict__ fln_b,
    const float* __restrict__ ff_w1,  const float* __restrict__ ff_b1,
    const float* __restrict__ ff_w2,  const float* __restrict__ ff_b2,
    const float* __restrict__ head_r, const float* __restrict__ last_w,
    const float* __restrict__ last_b,
    int* __restrict__ outp, float* __restrict__ ws)
{
  const int tid  = threadIdx.x;
  const int b    = blockIdx.x;
  const int lane = tid & 63;
  const int wid  = tid >> 6;

  int*   flags  = (int*)ws;                 // 16 KB, zeroed by memset
  float* embt   = ws + 4096;                // 256*512
  float* ycond  = embt + NCLS*DM;           // 512*512
  float* kvc    = ycond + TT*DM;            // 8*32*1024
  float* hq     = kvc + LAYERS*WIN*2*DM;    // 512
  float* xacc   = hq + DM;                  // 2*512 (ping-pong accumulators)
  float* xc2acc = xacc + 2*DM;              // 512
  float* logitb = xc2acc + DM;              // 256
  float* o_wT   = logitb + NCLS;            // 8*512*512 transposed o_w

  __shared__ __align__(16) float s_wA[6*DM];   // kv/q rows
  __shared__ __align__(16) float s_wB[8*DM];   // ff1 rows
  __shared__ __align__(16) float s_wC[8*DM];   // w2T slice [j][r]
  __shared__ __align__(16) float s_wO[2*DM];   // o_wT rows
  __shared__ __align__(16) float s_wL[DM];     // last_w row
  __shared__ __align__(16) float s_xc[DM];
  __shared__ __align__(16) float s_tmp[DM];
  __shared__ __align__(16) float s_q[DHD];
  __shared__ float s_part[BLK];
  __shared__ float s_red[8];
  __shared__ float s_h8[8];
  __shared__ int   s_ired[4];
  __shared__ float s_y[MEL];

  int ph = 0;

  // ======== one-time precompute ========
  {
    const int gtid = b*BLK + tid;
    for (int i = gtid; i < NCLS*DM; i += GRID*BLK) st_sc(embt + i, tanhf(emb[i]));
  }
  // ycond: block b owns t = b*2, b*2+1
  for (int k = 0; k < 2; k++){
    int t0 = b*2 + k;
    if (tid < MEL) s_y[tid] = y[tid*TT + t0];
    __syncthreads();
    for (int dd = tid; dd < DM; dd += BLK){
      const float* cw = condW + dd*MEL;
      float acc = 0.f;
#pragma unroll
      for (int m4 = 0; m4 < MEL; m4 += 4){
        float4 c4 = *(const float4*)(cw + m4);
        acc += c4.x*s_y[m4] + c4.y*s_y[m4+1] + c4.z*s_y[m4+2] + c4.w*s_y[m4+3];
      }
      st_sc(ycond + t0*DM + dd, acc);
    }
    __syncthreads();
  }
  // o_wT[l][c][r] = o_w[l][r][c]; block b: layer b>>5, rows (b&31)*16..+16
  {
    int l = b >> 5, r0 = (b & 31)*16;
    for (int rr = 0; rr < 16; rr++){
      int r = r0 + rr;
      const float* src = o_w + ((size_t)l*DM + r)*DM;
      float v0 = src[tid], v1 = src[tid+256];
      st_sc(o_wT + ((size_t)l*DM + tid)*DM + r, v0);
      st_sc(o_wT + ((size_t)l*DM + tid+256)*DM + r, v1);
    }
  }
  ph++;
  bar_arrive(flags, b, ph);
  pf_kvq(kv_w, q_w, 0, b, s_wA);
  bar_wait(flags, ph);

  int cur_idx = NCLS/2 - 1;
  const float scale = 0.125f;
  const int hh = b >> 5, gg = b & 31;     // attention assignment

  for (int t = 0; t < TT; t++){
    float* cond = ycond + t*DM;
    const int slot = t & (WIN-1);
    const int wlo  = (t >= WIN-1) ? 0 : (WIN-1 - t);

    for (int l = 0; l < LAYERS; l++){
      // ========== seg1: xc, LN1, KV/Q matvec; zero/seed accumulators ==========
      {
        float2 xv = (l == 0) ? *(const float2*)(embt + cur_idx*DM + 2*tid)
                             : ld_sc2(xacc + (l&1)*DM + 2*tid);
        float2 cv = *(const float2*)(cond + 2*tid);
        s_xc[2*tid]   = cv.x + xv.x;
        s_xc[2*tid+1] = cv.y + xv.y;
        if (tid < 2) st_sc(xacc + ((l+1)&1)*DM + b*2 + tid, 0.f);  // zero next-x acc
      }
      __syncthreads();
      {
        float part = s_xc[tid] + s_xc[tid + BLK];
        float wsum = wredsum(part);
        if (lane == 0) s_red[wid] = wsum;
        __syncthreads();
        float mu = (s_red[0]+s_red[1]+s_red[2]+s_red[3]) * (1.0f/DM);
        float d0 = s_xc[tid] - mu, d1 = s_xc[tid+BLK] - mu;
        float vs = wredsum(d0*d0 + d1*d1);
        __syncthreads();
        if (lane == 0) s_red[wid] = vs;
        __syncthreads();
        float var  = (s_red[0]+s_red[1]+s_red[2]+s_red[3]) * (1.0f/DM);
        float rsig = 1.0f / sqrtf(var + 1e-5f);
        const float* lw = ln_w + l*DM; const float* lb = ln_b + l*DM;
        s_tmp[tid]     = (s_xc[tid]     - mu)*rsig*lw[tid]     + lb[tid];
        s_tmp[tid+BLK] = (s_xc[tid+BLK] - mu)*rsig*lw[tid+BLK] + lb[tid+BLK];
      }
      __syncthreads();
      {
        // seed xc2acc rows with xc + o_b (row-owner)
        if (tid < 2){
          int r = b*2 + tid;
          st_sc(xc2acc + r, s_xc[r] + o_b[l*DM + r]);
        }
        float* cacheRow = kvc + ((size_t)(l*WIN + slot) << 10);
        for (int j = wid; j < 6; j += 4){
          int r = b*6 + j;
          float dv = dot512(s_wA + j*DM, s_tmp, lane);
          if (r < 2*DM){
            dv += kv_b[l*2*DM + r];
            if (lane == 0) st_sc(cacheRow + r, dv);
          } else {
            int rq = r - 2*DM;
            dv += q_b[l*DM + rq];
            if (lane == 0) st_sc(hq + rq, dv);
          }
        }
      }
      ph++;
      bar_arrive(flags, b, ph);
      pf_copy(ff_w1 + ((size_t)l*DFF + b*8)*DM, s_wB, 8*128);
      pf_copy(o_wT + ((size_t)(l*DM + hh*DHD + gg*2))*DM, s_wO, 2*128);
      bar_wait(flags, ph);

      // ========== seg2: distributed attention + o_w partial ==========
      {
        // issue K partial loads early (independent of q)
        int w = tid >> 3, j = tid & 7;
        int c = (t + 1 + w) & (WIN-1);
        float* kk = kvc + ((size_t)(l*WIN + c) << 10) + hh*DHD + j*8;
        float2 k0 = ld_sc2(kk), k1 = ld_sc2(kk+2), k2 = ld_sc2(kk+4), k3 = ld_sc2(kk+6);
        float2 v2 = make_float2(0.f, 0.f);
        if (tid < 32){
          int cv2 = (t + 1 + tid) & (WIN-1);
          v2 = ld_sc2(kvc + ((size_t)(l*WIN + cv2) << 10) + DM + hh*DHD + gg*2);
          float2 qv = ld_sc2(hq + hh*DHD + 2*tid);
          s_q[2*tid] = qv.x; s_q[2*tid+1] = qv.y;
        }
        __syncthreads();
        const float* rr = head_r + (((size_t)(l*WIN + w)*NH + hh) << 6) + j*8;
        float2 r0 = *(const float2*)(rr),   r1 = *(const float2*)(rr+2);
        float2 r2 = *(const float2*)(rr+4), r3 = *(const float2*)(rr+6);
        const float* qq = s_q + j*8;
        float acc = (k0.x+r0.x)*qq[0] + (k0.y+r0.y)*qq[1]
                  + (k1.x+r1.x)*qq[2] + (k1.y+r1.y)*qq[3]
                  + (k2.x+r2.x)*qq[4] + (k2.y+r2.y)*qq[5]
                  + (k3.x+r3.x)*qq[6] + (k3.y+r3.y)*qq[7];
        s_part[tid] = acc;
        __syncthreads();
        if (tid < 32){
          float sc = 0.f;
#pragma unroll
          for (int jj = 0; jj < 8; jj++) sc += s_part[tid*8 + jj];
          sc *= scale;
          float sval = (tid >= wlo) ? sc : -INFINITY;
          float m = sval;
#pragma unroll
          for (int mm = 16; mm >= 1; mm >>= 1) m = fmaxf(m, __shfl_xor(m, mm, 64));
          float p = (tid >= wlo) ? expf(sval - m) : 0.f;
          float den = p;
#pragma unroll
          for (int mm = 16; mm >= 1; mm >>= 1) den += __shfl_xor(den, mm, 64);
          float at = p / den;
          float ox = at*v2.x, oy = at*v2.y;
#pragma unroll
          for (int mm = 16; mm >= 1; mm >>= 1){
            ox += __shfl_xor(ox, mm, 64); oy += __shfl_xor(oy, mm, 64);
          }
          if (tid == 0){ s_red[0] = ox; s_red[1] = oy; }
        }
        __syncthreads();
        float o0 = s_red[0], o1 = s_red[1];
        float p0 = s_wO[tid]*o0     + s_wO[DM + tid]*o1;
        float p1 = s_wO[tid+256]*o0 + s_wO[DM + tid+256]*o1;
        unsafeAtomicAdd(xc2acc + tid,       p0);
        unsafeAtomicAdd(xc2acc + tid + 256, p1);
      }
      ph++;
      bar_arrive(flags, b, ph);
      {  // prefetch w2T slice: s_wC[j][r] = ff_w2[l][r][b*8+j]
        for (int rr2 = tid; rr2 < DM; rr2 += BLK){
          const float* src = ff_w2 + ((size_t)l*DM + rr2)*DFF + b*8;
          float4 a = *(const float4*)(src);
          float4 c4 = *(const float4*)(src + 4);
          s_wC[0*DM+rr2]=a.x;  s_wC[1*DM+rr2]=a.y;  s_wC[2*DM+rr2]=a.z;  s_wC[3*DM+rr2]=a.w;
          s_wC[4*DM+rr2]=c4.x; s_wC[5*DM+rr2]=c4.y; s_wC[6*DM+rr2]=c4.z; s_wC[7*DM+rr2]=c4.w;
        }
      }
      bar_wait(flags, ph);

      // ========== seg3: LN2 + FFN1 + FFN2-partial (fused) ==========
      {
        float2 x2 = ld_sc2(xc2acc + 2*tid);
        s_xc[2*tid] = x2.x; s_xc[2*tid+1] = x2.y;
      }
      __syncthreads();
      {
        float part = s_xc[tid] + s_xc[tid + BLK];
        float wsum = wredsum(part);
        if (lane == 0) s_red[wid] = wsum;
        __syncthreads();
        float mu = (s_red[0]+s_red[1]+s_red[2]+s_red[3]) * (1.0f/DM);
        float d0 = s_xc[tid] - mu, d1 = s_xc[tid+BLK] - mu;
        float vs = wredsum(d0*d0 + d1*d1);
        __syncthreads();
        if (lane == 0) s_red[wid] = vs;
        __syncthreads();
        float var  = (s_red[0]+s_red[1]+s_red[2]+s_red[3]) * (1.0f/DM);
        float rsig = 1.0f / sqrtf(var + 1e-5f);
        const float* fw = fln_w + l*DM; const float* fb = fln_b + l*DM;
        s_tmp[tid]     = (s_xc[tid]     - mu)*rsig*fw[tid]     + fb[tid];
        s_tmp[tid+BLK] = (s_xc[tid+BLK] - mu)*rsig*fw[tid+BLK] + fb[tid+BLK];
      }
      __syncthreads();
      {
        for (int j2 = 0; j2 < 2; j2++){
          int j = wid*2 + j2;
          float dv = dot512(s_wB + j*DM, s_tmp, lane) + ff_b1[l*DFF + b*8 + j];
          if (lane == 0) s_h8[j] = gelu_tanh(dv);
        }
      }
      __syncthreads();
      {
        float h0=s_h8[0], h1=s_h8[1], h2=s_h8[2], h3=s_h8[3];
        float h4=s_h8[4], h5=s_h8[5], h6=s_h8[6], h7=s_h8[7];
        int r0 = tid, r1 = tid + 256;
        float p0 = s_wC[r0]*h0 + s_wC[DM+r0]*h1 + s_wC[2*DM+r0]*h2 + s_wC[3*DM+r0]*h3
                 + s_wC[4*DM+r0]*h4 + s_wC[5*DM+r0]*h5 + s_wC[6*DM+r0]*h6 + s_wC[7*DM+r0]*h7;
        float p1 = s_wC[r1]*h0 + s_wC[DM+r1]*h1 + s_wC[2*DM+r1]*h2 + s_wC[3*DM+r1]*h3
                 + s_wC[4*DM+r1]*h4 + s_wC[5*DM+r1]*h5 + s_wC[6*DM+r1]*h6 + s_wC[7*DM+r1]*h7;
        // row-owner adds base term xc2 + b2
        if (r0 == b*2)     p0 += s_xc[r0] + ff_b2[l*DM + r0];
        if (r0 == b*2 + 1) p0 += s_xc[r0] + ff_b2[l*DM + r0];
        if (r1 == b*2)     p1 += s_xc[r1] + ff_b2[l*DM + r1];
        if (r1 == b*2 + 1) p1 += s_xc[r1] + ff_b2[l*DM + r1];
        float* xn = xacc + ((l+1)&1)*DM;
        unsafeAtomicAdd(xn + r0, p0);
        unsafeAtomicAdd(xn + r1, p1);
      }
      ph++;
      bar_arrive(flags, b, ph);
      if (l < LAYERS-1) pf_kvq(kv_w, q_w, l+1, b, s_wA);
      else              pf_copy(last_w + (size_t)b*DM, s_wL, 128);
      bar_wait(flags, ph);
    } // layers

    // ========== head: logits (1 row per block) ==========
    {
      float2 x2 = ld_sc2(xacc + 2*tid);   // x8 lives in xacc[0]
      s_tmp[2*tid] = x2.x; s_tmp[2*tid+1] = x2.y;
    }
    __syncthreads();
    if (wid == 0){
      float dv = dot512(s_wL, s_tmp, lane) + last_b[b];
      if (lane == 0) st_sc(logitb + b, dv);
    }
    ph++;
    bar_arrive(flags, b, ph);
    pf_kvq(kv_w, q_w, 0, b, s_wA);        // layer-0 weights for next step
    bar_wait(flags, ph);

    // ===== sampling (redundant per block; deterministic within run; no barrier) =====
    {
      float u  = samples[t];
      float li = ld_sc(logitb + tid);
      float mx = wredmax(li);
      if (lane == 0) s_red[wid] = mx;
      __syncthreads();
      mx = fmaxf(fmaxf(s_red[0], s_red[1]), fmaxf(s_red[2], s_red[3]));
      float p  = expf(li - mx);
      float sm = wredsum(p);
      __syncthreads();
      if (lane == 0) s_red[wid] = sm;
      __syncthreads();
      float den = s_red[0]+s_red[1]+s_red[2]+s_red[3];
      float q = p / den;
      float x = q;
#pragma unroll
      for (int off = 1; off < 64; off <<= 1){
        float n = __shfl_up(x, off, 64);
        if (lane >= off) x += n;
      }
      __syncthreads();
      if (lane == 63) s_red[wid] = x;
      __syncthreads();
      float offs = 0.f;
      for (int j2 = 0; j2 < wid; j2++) offs += s_red[j2];
      float cum = x + offs;
      unsigned long long bal = __ballot(cum > u);
      int first = (bal != 0ULL) ? (__ffsll(bal) - 1) : 9999;
      if (lane == 0) s_ired[wid] = (first < 9999) ? (wid*64 + first) : 9999;
      __syncthreads();
      int idx = min(min(s_ired[0], s_ired[1]), min(s_ired[2], s_ired[3]));
      if (idx == 9999) idx = 0;
      cur_idx = idx;
      if (b == 0 && tid == 0) outp[t] = idx;
      __syncthreads();
    }
  } // t
}

extern "C" void kernel_launch(void* const* d_in, const int* in_sizes, int n_in,
                              void* d_out, int out_size, void* d_ws, size_t ws_size,
                              hipStream_t stream)
{
  (void)in_sizes; (void)n_in; (void)out_size; (void)ws_size;
  hipMemsetAsync(d_ws, 0, 16384, stream);   // zero barrier flags

  const float* y      = (const float*)d_in[0];
  const float* samp   = (const float*)d_in[1];
  const float* emb    = (const float*)d_in[2];
  const float* condW  = (const float*)d_in[3];
  const float* ln_w   = (const float*)d_in[4];
  const float* ln_b   = (const float*)d_in[5];
  const float* kv_w   = (const float*)d_in[6];
  const float* kv_b   = (const float*)d_in[7];
  const float* q_w    = (const float*)d_in[8];
  const float* q_b    = (const float*)d_in[9];
  const float* o_w    = (const float*)d_in[10];
  const float* o_b    = (const float*)d_in[11];
  const float* fln_w  = (const float*)d_in[12];
  const float* fln_b  = (const float*)d_in[13];
  const float* ff_w1  = (const float*)d_in[14];
  const float* ff_b1  = (const float*)d_in[15];
  const float* ff_w2  = (const float*)d_in[16];
  const float* ff_b2  = (const float*)d_in[17];
  const float* head_r = (const float*)d_in[18];
  const float* last_w = (const float*)d_in[19];
  const float* last_b = (const float*)d_in[20];

  wf_kernel<<<GRID, BLK, 0, stream>>>(y, samp, emb, condW, ln_w, ln_b, kv_w, kv_b,
                                      q_w, q_b, o_w, o_b, fln_w, fln_b,
                                      ff_w1, ff_b1, ff_w2, ff_b2, head_r,
                                      last_w, last_b,
                                      (int*)d_out, (float*)d_ws);
}

// Round 5
// 65827.289 us; speedup vs baseline: 3.2021x; 1.3543x over previous
//
#include <hip/hip_runtime.h>
#include <math.h>

// ---- model dims ----
#define LAYERS 8
#define WIN    32
#define NH     8
#define DHD    64
#define DM     512
#define DFF    2048
#define NCLS   256
#define MEL    80
#define TT     512

// ---- persistent kernel: 256 blocks x 256 threads (1 block/CU) ----
#define GRID   256
#define BLK    256

typedef unsigned short u16;
typedef unsigned long long u64;

// ---- wave=64 reductions ----
__device__ inline float wredsum(float v){
#pragma unroll
  for (int m = 32; m >= 1; m >>= 1) v += __shfl_xor(v, m, 64);
  return v;
}
__device__ inline float wredmax(float v){
#pragma unroll
  for (int m = 32; m >= 1; m >>= 1) v = fmaxf(v, __shfl_xor(v, m, 64));
  return v;
}

// ---- coherent (sc-bit) comm ops: relaxed agent scope, no cache maintenance ----
__device__ inline float ld_sc(float* p){
  return __hip_atomic_load(p, __ATOMIC_RELAXED, __HIP_MEMORY_SCOPE_AGENT);
}
__device__ inline void st_sc(float* p, float v){
  __hip_atomic_store(p, v, __ATOMIC_RELAXED, __HIP_MEMORY_SCOPE_AGENT);
}
__device__ inline float2 ld_sc2(float* p){
  u64 u = __hip_atomic_load((u64*)p, __ATOMIC_RELAXED, __HIP_MEMORY_SCOPE_AGENT);
  union { u64 u; float2 f; } cv; cv.u = u; return cv.f;
}

// dot(row512_in_LDS, vec512_in_LDS) across one wave
__device__ inline float dot512(const float* w, const float* vec, int lane){
  float4 a0 = *(const float4*)(w + 4*lane);
  float4 a1 = *(const float4*)(w + 256 + 4*lane);
  float4 b0 = *(const float4*)(vec + 4*lane);
  float4 b1 = *(const float4*)(vec + 256 + 4*lane);
  float p = a0.x*b0.x + a0.y*b0.y + a0.z*b0.z + a0.w*b0.w
          + a1.x*b1.x + a1.y*b1.y + a1.z*b1.z + a1.w*b1.w;
  return wredsum(p);
}

__device__ inline float gelu_tanh(float x){
  float x3 = x*x*x;
  return 0.5f*x*(1.0f + tanhf(0.7978845608028654f*(x + 0.044715f*x3)));
}

// ---- split-phase barrier: packed u16 flags (max phase 12801 < 65535) ----
__device__ inline void bar_arrive(u16* flags, int b, int ph){
  __syncthreads();   // drains vmcnt: all sc stores/atomics of this block visible
  if (threadIdx.x == 0)
    __hip_atomic_store(flags + b, (u16)ph, __ATOMIC_RELAXED, __HIP_MEMORY_SCOPE_AGENT);
}
__device__ inline void bar_wait(u16* flags, int ph){
  int tid = threadIdx.x;
  if (tid < 64){
    u64* fp = (u64*)flags + tid;    // lane i watches flags[4i..4i+4)
    for (;;){
      u64 v = __hip_atomic_load(fp, __ATOMIC_RELAXED, __HIP_MEMORY_SCOPE_AGENT);
      int a0 = (int)(v & 0xffff), a1 = (int)((v >> 16) & 0xffff);
      int a2 = (int)((v >> 32) & 0xffff), a3 = (int)(v >> 48);
      if (min(min(a0, a1), min(a2, a3)) >= ph) break;
      __builtin_amdgcn_s_sleep(2);
    }
  }
  asm volatile("" ::: "memory");
  __syncthreads();
}

// float4 global->LDS copy (all threads), n4 = count of float4
__device__ inline void pf_copy(const float* __restrict__ g, float* l, int n4){
  const float4* g4 = (const float4*)g;
  float4* l4 = (float4*)l;
#pragma unroll 4
  for (int i = threadIdx.x; i < n4; i += BLK) l4[i] = g4[i];
}

// prefetch this block's 6 kv/q rows for layer l into s_wA (3072 floats)
__device__ inline void pf_kvq(const float* kv_w, const float* q_w, int l, int b, float* s_wA){
  for (int i = threadIdx.x; i < 768; i += BLK){
    int j = i >> 7, off = i & 127;
    int r = b*6 + j;
    float4 v;
    if (r < 2*DM) v = ((const float4*)(kv_w + ((size_t)l*2*DM + r)*DM))[off];
    else          v = ((const float4*)(q_w  + ((size_t)l*DM + (r-2*DM))*DM))[off];
    ((float4*)(s_wA + j*DM))[off] = v;
  }
}

__global__ __launch_bounds__(BLK, 1) void wf_kernel(
    const float* __restrict__ y,      const float* __restrict__ samples,
    const float* __restrict__ emb,    const float* __restrict__ condW,
    const float* __restrict__ ln_w,   const float* __restrict__ ln_b,
    const float* __restrict__ kv_w,   const float* __restrict__ kv_b,
    const float* __restrict__ q_w,    const float* __restrict__ q_b,
    const float* __restrict__ o_w,    const float* __restrict__ o_b,
    const float* __restrict__ fln_w,  const float* __restrict__ fln_b,
    const float* __restrict__ ff_w1,  const float* __restrict__ ff_b1,
    const float* __restrict__ ff_w2,  const float* __restrict__ ff_b2,
    const float* __restrict__ head_r, const float* __restrict__ last_w,
    const float* __restrict__ last_b,
    int* __restrict__ outp, float* __restrict__ ws)
{
  const int tid  = threadIdx.x;
  const int b    = blockIdx.x;
  const int lane = tid & 63;
  const int wid  = tid >> 6;
  const int kz   = b >> 5;            // partial-accumulator index (fan-in 32)
  const int ez0  = (b & 31) * 16;     // 16 accumulator elements this block maintains

  u16*   flags  = (u16*)ws;                 // 512 B, zeroed by memset
  float* embt   = ws + 4096;                // 256*512
  float* ycond  = embt + NCLS*DM;           // 512*512
  float* kvc    = ycond + TT*DM;            // 8*32*1024
  float* hq     = kvc + LAYERS*WIN*2*DM;    // 512
  float* xpart  = hq + DM;                  // [2][8][512] ping-pong x partials
  float* xc2p   = xpart + 2*8*DM;           // [8][512] xc2 partials
  float* logitb = xc2p + 8*DM;              // 256
  float* o_wT   = logitb + NCLS;            // 8*512*512 transposed o_w

  __shared__ __align__(16) float s_wA[6*DM];   // kv/q rows
  __shared__ __align__(16) float s_wB[8*DM];   // ff1 rows
  __shared__ __align__(16) float s_wC[8*DM];   // w2T slice [j][r]
  __shared__ __align__(16) float s_wO[2*DM];   // o_wT rows
  __shared__ __align__(16) float s_wL[DM];     // last_w row
  __shared__ __align__(16) float s_xc[DM];
  __shared__ __align__(16) float s_tmp[DM];
  __shared__ __align__(16) float s_q[DHD];
  __shared__ float s_part[BLK];
  __shared__ float s_red[8];
  __shared__ float s_h8[8];
  __shared__ int   s_ired[4];
  __shared__ float s_y[MEL];

  int ph = 0;

  // ======== one-time precompute ========
  {
    const int gtid = b*BLK + tid;
    for (int i = gtid; i < NCLS*DM; i += GRID*BLK) st_sc(embt + i, tanhf(emb[i]));
  }
  for (int k = 0; k < 2; k++){
    int t0 = b*2 + k;
    if (tid < MEL) s_y[tid] = y[tid*TT + t0];
    __syncthreads();
    for (int dd = tid; dd < DM; dd += BLK){
      const float* cw = condW + dd*MEL;
      float acc = 0.f;
#pragma unroll
      for (int m4 = 0; m4 < MEL; m4 += 4){
        float4 c4 = *(const float4*)(cw + m4);
        acc += c4.x*s_y[m4] + c4.y*s_y[m4+1] + c4.z*s_y[m4+2] + c4.w*s_y[m4+3];
      }
      st_sc(ycond + t0*DM + dd, acc);
    }
    __syncthreads();
  }
  // o_wT[l][c][r] = o_w[l][r][c]
  {
    int l = b >> 5, r0 = (b & 31)*16;
    for (int rr = 0; rr < 16; rr++){
      int r = r0 + rr;
      const float* src = o_w + ((size_t)l*DM + r)*DM;
      float v0 = src[tid], v1 = src[tid+256];
      st_sc(o_wT + ((size_t)l*DM + tid)*DM + r, v0);
      st_sc(o_wT + ((size_t)l*DM + tid+256)*DM + r, v1);
    }
  }
  ph++;
  bar_arrive(flags, b, ph);
  pf_kvq(kv_w, q_w, 0, b, s_wA);
  bar_wait(flags, ph);

  int cur_idx = NCLS/2 - 1;
  const float scale = 0.125f;
  const int hh = b >> 5, gg = b & 31;     // attention assignment

  for (int t = 0; t < TT; t++){
    float* cond = ycond + t*DM;
    const int slot = t & (WIN-1);
    const int wlo  = (t >= WIN-1) ? 0 : (WIN-1 - t);

    for (int l = 0; l < LAYERS; l++){
      float* xcur = xpart + (l&1)*8*DM;        // read partials (l>0)
      float* xnxt = xpart + ((l+1)&1)*8*DM;    // target partials for next x

      // ========== seg1: xc (gather), LN1, KV/Q matvec; zero/seed partials ==========
      {
        float2 xv;
        if (l == 0){
          xv = *(const float2*)(embt + cur_idx*DM + 2*tid);
        } else {
          xv = make_float2(0.f, 0.f);
#pragma unroll
          for (int k = 0; k < 8; k++){
            float2 p = ld_sc2(xcur + k*DM + 2*tid);
            xv.x += p.x; xv.y += p.y;
          }
        }
        float2 cv = *(const float2*)(cond + 2*tid);
        s_xc[2*tid]   = cv.x + xv.x;
        s_xc[2*tid+1] = cv.y + xv.y;
      }
      __syncthreads();
      {
        float part = s_xc[tid] + s_xc[tid + BLK];
        float wsum = wredsum(part);
        if (lane == 0) s_red[wid] = wsum;
        __syncthreads();
        float mu = (s_red[0]+s_red[1]+s_red[2]+s_red[3]) * (1.0f/DM);
        float d0 = s_xc[tid] - mu, d1 = s_xc[tid+BLK] - mu;
        float vs = wredsum(d0*d0 + d1*d1);
        __syncthreads();
        if (lane == 0) s_red[wid] = vs;
        __syncthreads();
        float var  = (s_red[0]+s_red[1]+s_red[2]+s_red[3]) * (1.0f/DM);
        float rsig = 1.0f / sqrtf(var + 1e-5f);
        const float* lw = ln_w + l*DM; const float* lb = ln_b + l*DM;
        s_tmp[tid]     = (s_xc[tid]     - mu)*rsig*lw[tid]     + lb[tid];
        s_tmp[tid+BLK] = (s_xc[tid+BLK] - mu)*rsig*lw[tid+BLK] + lb[tid+BLK];
      }
      __syncthreads();
      {
        // zero next-x partial; zero-or-seed xc2 partial (16 els each, single writer)
        if (tid < 16){
          int e = ez0 + tid;
          st_sc(xnxt + kz*DM + e, 0.f);
          float seed = (kz == 0) ? s_xc[e] + o_b[l*DM + e] : 0.f;
          st_sc(xc2p + kz*DM + e, seed);
        }
        float* cacheRow = kvc + ((size_t)(l*WIN + slot) << 10);
        for (int j = wid; j < 6; j += 4){
          int r = b*6 + j;
          float dv = dot512(s_wA + j*DM, s_tmp, lane);
          if (r < 2*DM){
            dv += kv_b[l*2*DM + r];
            if (lane == 0) st_sc(cacheRow + r, dv);
          } else {
            int rq = r - 2*DM;
            dv += q_b[l*DM + rq];
            if (lane == 0) st_sc(hq + rq, dv);
          }
        }
      }
      ph++;
      bar_arrive(flags, b, ph);
      pf_copy(ff_w1 + ((size_t)l*DFF + b*8)*DM, s_wB, 8*128);
      pf_copy(o_wT + ((size_t)(l*DM + hh*DHD + gg*2))*DM, s_wO, 2*128);
      bar_wait(flags, ph);

      // ========== seg2: distributed attention + o_w partial (8-way partials) ==========
      {
        int w = tid >> 3, j = tid & 7;
        int c = (t + 1 + w) & (WIN-1);
        float* kk = kvc + ((size_t)(l*WIN + c) << 10) + hh*DHD + j*8;
        float2 k0 = ld_sc2(kk), k1 = ld_sc2(kk+2), k2 = ld_sc2(kk+4), k3 = ld_sc2(kk+6);
        float2 v2 = make_float2(0.f, 0.f);
        if (tid < 32){
          int cv2 = (t + 1 + tid) & (WIN-1);
          v2 = ld_sc2(kvc + ((size_t)(l*WIN + cv2) << 10) + DM + hh*DHD + gg*2);
          float2 qv = ld_sc2(hq + hh*DHD + 2*tid);
          s_q[2*tid] = qv.x; s_q[2*tid+1] = qv.y;
        }
        __syncthreads();
        const float* rr = head_r + (((size_t)(l*WIN + w)*NH + hh) << 6) + j*8;
        float2 r0 = *(const float2*)(rr),   r1 = *(const float2*)(rr+2);
        float2 r2 = *(const float2*)(rr+4), r3 = *(const float2*)(rr+6);
        const float* qq = s_q + j*8;
        float acc = (k0.x+r0.x)*qq[0] + (k0.y+r0.y)*qq[1]
                  + (k1.x+r1.x)*qq[2] + (k1.y+r1.y)*qq[3]
                  + (k2.x+r2.x)*qq[4] + (k2.y+r2.y)*qq[5]
                  + (k3.x+r3.x)*qq[6] + (k3.y+r3.y)*qq[7];
        s_part[tid] = acc;
        __syncthreads();
        if (tid < 32){
          float sc = 0.f;
#pragma unroll
          for (int jj = 0; jj < 8; jj++) sc += s_part[tid*8 + jj];
          sc *= scale;
          float sval = (tid >= wlo) ? sc : -INFINITY;
          float m = sval;
#pragma unroll
          for (int mm = 16; mm >= 1; mm >>= 1) m = fmaxf(m, __shfl_xor(m, mm, 64));
          float p = (tid >= wlo) ? expf(sval - m) : 0.f;
          float den = p;
#pragma unroll
          for (int mm = 16; mm >= 1; mm >>= 1) den += __shfl_xor(den, mm, 64);
          float at = p / den;
          float ox = at*v2.x, oy = at*v2.y;
#pragma unroll
          for (int mm = 16; mm >= 1; mm >>= 1){
            ox += __shfl_xor(ox, mm, 64); oy += __shfl_xor(oy, mm, 64);
          }
          if (tid == 0){ s_red[0] = ox; s_red[1] = oy; }
        }
        __syncthreads();
        float o0 = s_red[0], o1 = s_red[1];
        float p0 = s_wO[tid]*o0     + s_wO[DM + tid]*o1;
        float p1 = s_wO[tid+256]*o0 + s_wO[DM + tid+256]*o1;
        unsafeAtomicAdd(xc2p + kz*DM + tid,       p0);
        unsafeAtomicAdd(xc2p + kz*DM + tid + 256, p1);
      }
      ph++;
      bar_arrive(flags, b, ph);
      {  // prefetch w2T slice: s_wC[j][r] = ff_w2[l][r][b*8+j]
        for (int rr2 = tid; rr2 < DM; rr2 += BLK){
          const float* src = ff_w2 + ((size_t)l*DM + rr2)*DFF + b*8;
          float4 a = *(const float4*)(src);
          float4 c4 = *(const float4*)(src + 4);
          s_wC[0*DM+rr2]=a.x;  s_wC[1*DM+rr2]=a.y;  s_wC[2*DM+rr2]=a.z;  s_wC[3*DM+rr2]=a.w;
          s_wC[4*DM+rr2]=c4.x; s_wC[5*DM+rr2]=c4.y; s_wC[6*DM+rr2]=c4.z; s_wC[7*DM+rr2]=c4.w;
        }
      }
      bar_wait(flags, ph);

      // ========== seg3: gather xc2, LN2 + FFN1 + FFN2-partial (fused) ==========
      {
        float2 x2 = make_float2(0.f, 0.f);
#pragma unroll
        for (int k = 0; k < 8; k++){
          float2 p = ld_sc2(xc2p + k*DM + 2*tid);
          x2.x += p.x; x2.y += p.y;
        }
        s_xc[2*tid] = x2.x; s_xc[2*tid+1] = x2.y;
      }
      __syncthreads();
      {
        float part = s_xc[tid] + s_xc[tid + BLK];
        float wsum = wredsum(part);
        if (lane == 0) s_red[wid] = wsum;
        __syncthreads();
        float mu = (s_red[0]+s_red[1]+s_red[2]+s_red[3]) * (1.0f/DM);
        float d0 = s_xc[tid] - mu, d1 = s_xc[tid+BLK] - mu;
        float vs = wredsum(d0*d0 + d1*d1);
        __syncthreads();
        if (lane == 0) s_red[wid] = vs;
        __syncthreads();
        float var  = (s_red[0]+s_red[1]+s_red[2]+s_red[3]) * (1.0f/DM);
        float rsig = 1.0f / sqrtf(var + 1e-5f);
        const float* fw = fln_w + l*DM; const float* fb = fln_b + l*DM;
        s_tmp[tid]     = (s_xc[tid]     - mu)*rsig*fw[tid]     + fb[tid];
        s_tmp[tid+BLK] = (s_xc[tid+BLK] - mu)*rsig*fw[tid+BLK] + fb[tid+BLK];
      }
      __syncthreads();
      {
        for (int j2 = 0; j2 < 2; j2++){
          int j = wid*2 + j2;
          float dv = dot512(s_wB + j*DM, s_tmp, lane) + ff_b1[l*DFF + b*8 + j];
          if (lane == 0) s_h8[j] = gelu_tanh(dv);
        }
      }
      __syncthreads();
      {
        float h0=s_h8[0], h1=s_h8[1], h2=s_h8[2], h3=s_h8[3];
        float h4=s_h8[4], h5=s_h8[5], h6=s_h8[6], h7=s_h8[7];
        int r0 = tid, r1 = tid + 256;
        float p0 = s_wC[r0]*h0 + s_wC[DM+r0]*h1 + s_wC[2*DM+r0]*h2 + s_wC[3*DM+r0]*h3
                 + s_wC[4*DM+r0]*h4 + s_wC[5*DM+r0]*h5 + s_wC[6*DM+r0]*h6 + s_wC[7*DM+r0]*h7;
        float p1 = s_wC[r1]*h0 + s_wC[DM+r1]*h1 + s_wC[2*DM+r1]*h2 + s_wC[3*DM+r1]*h3
                 + s_wC[4*DM+r1]*h4 + s_wC[5*DM+r1]*h5 + s_wC[6*DM+r1]*h6 + s_wC[7*DM+r1]*h7;
        if (r0 == b*2)     p0 += s_xc[r0] + ff_b2[l*DM + r0];
        if (r0 == b*2 + 1) p0 += s_xc[r0] + ff_b2[l*DM + r0];
        if (r1 == b*2)     p1 += s_xc[r1] + ff_b2[l*DM + r1];
        if (r1 == b*2 + 1) p1 += s_xc[r1] + ff_b2[l*DM + r1];
        unsafeAtomicAdd(xnxt + kz*DM + r0, p0);
        unsafeAtomicAdd(xnxt + kz*DM + r1, p1);
      }
      ph++;
      bar_arrive(flags, b, ph);
      if (l < LAYERS-1) pf_kvq(kv_w, q_w, l+1, b, s_wA);
      else              pf_copy(last_w + (size_t)b*DM, s_wL, 128);
      bar_wait(flags, ph);
    } // layers

    // ========== head: gather x8 + logits (1 row per block) ==========
    {
      float2 xv = make_float2(0.f, 0.f);
#pragma unroll
      for (int k = 0; k < 8; k++){
        float2 p = ld_sc2(xpart + k*DM + 2*tid);    // x8 in xpart[0]
        xv.x += p.x; xv.y += p.y;
      }
      s_tmp[2*tid] = xv.x; s_tmp[2*tid+1] = xv.y;
    }
    __syncthreads();
    if (wid == 0){
      float dv = dot512(s_wL, s_tmp, lane) + last_b[b];
      if (lane == 0) st_sc(logitb + b, dv);
    }
    ph++;
    bar_arrive(flags, b, ph);
    pf_kvq(kv_w, q_w, 0, b, s_wA);        // layer-0 weights for next step
    bar_wait(flags, ph);

    // ===== sampling (redundant per block; deterministic within run; no barrier) =====
    {
      float u  = samples[t];
      float li = ld_sc(logitb + tid);
      float mx = wredmax(li);
      if (lane == 0) s_red[wid] = mx;
      __syncthreads();
      mx = fmaxf(fmaxf(s_red[0], s_red[1]), fmaxf(s_red[2], s_red[3]));
      float p  = expf(li - mx);
      float sm = wredsum(p);
      __syncthreads();
      if (lane == 0) s_red[wid] = sm;
      __syncthreads();
      float den = s_red[0]+s_red[1]+s_red[2]+s_red[3];
      float q = p / den;
      float x = q;
#pragma unroll
      for (int off = 1; off < 64; off <<= 1){
        float n = __shfl_up(x, off, 64);
        if (lane >= off) x += n;
      }
      __syncthreads();
      if (lane == 63) s_red[wid] = x;
      __syncthreads();
      float offs = 0.f;
      for (int j2 = 0; j2 < wid; j2++) offs += s_red[j2];
      float cum = x + offs;
      unsigned long long bal = __ballot(cum > u);
      int first = (bal != 0ULL) ? (__ffsll(bal) - 1) : 9999;
      if (lane == 0) s_ired[wid] = (first < 9999) ? (wid*64 + first) : 9999;
      __syncthreads();
      int idx = min(min(s_ired[0], s_ired[1]), min(s_ired[2], s_ired[3]));
      if (idx == 9999) idx = 0;
      cur_idx = idx;
      if (b == 0 && tid == 0) outp[t] = idx;
      __syncthreads();
    }
  } // t
}

extern "C" void kernel_launch(void* const* d_in, const int* in_sizes, int n_in,
                              void* d_out, int out_size, void* d_ws, size_t ws_size,
                              hipStream_t stream)
{
  (void)in_sizes; (void)n_in; (void)out_size; (void)ws_size;
  hipMemsetAsync(d_ws, 0, 2048, stream);   // zero barrier flags

  const float* y      = (const float*)d_in[0];
  const float* samp   = (const float*)d_in[1];
  const float* emb    = (const float*)d_in[2];
  const float* condW  = (const float*)d_in[3];
  const float* ln_w   = (const float*)d_in[4];
  const float* ln_b   = (const float*)d_in[5];
  const float* kv_w   = (const float*)d_in[6];
  const float* kv_b   = (const float*)d_in[7];
  const float* q_w    = (const float*)d_in[8];
  const float* q_b    = (const float*)d_in[9];
  const float* o_w    = (const float*)d_in[10];
  const float* o_b    = (const float*)d_in[11];
  const float* fln_w  = (const float*)d_in[12];
  const float* fln_b  = (const float*)d_in[13];
  const float* ff_w1  = (const float*)d_in[14];
  const float* ff_b1  = (const float*)d_in[15];
  const float* ff_w2  = (const float*)d_in[16];
  const float* ff_b2  = (const float*)d_in[17];
  const float* head_r = (const float*)d_in[18];
  const float* last_w = (const float*)d_in[19];
  const float* last_b = (const float*)d_in[20];

  wf_kernel<<<GRID, BLK, 0, stream>>>(y, samp, emb, condW, ln_w, ln_b, kv_w, kv_b,
                                      q_w, q_b, o_w, o_b, fln_w, fln_b,
                                      ff_w1, ff_b1, ff_w2, ff_b2, head_r,
                                      last_w, last_b,
                                      (int*)d_out, (float*)d_ws);
}